// Round 12
// baseline (741.038 us; speedup 1.0000x reference)
//
#include <hip/hip_runtime.h>
#include <hip/hip_bf16.h>
#include <math.h>

#define Nn 50000
#define Ee 1600000
#define RR 3
#define RN (RR * Nn)
#define FIN 770
#define KPAD1 832   /* 13 x 64 */

typedef __attribute__((ext_vector_type(8))) short short8;
typedef __attribute__((ext_vector_type(4))) float floatx4;

static __device__ __forceinline__ unsigned short f2bf(float v) {
  __hip_bfloat16 h = __float2bfloat16(v);
  return *(unsigned short*)&h;
}

// ---------------------------------------------------------------------------
// CSR build: count (atomic, returns rank) -> exclusive scan -> atomic-free fill
// ---------------------------------------------------------------------------
__global__ __launch_bounds__(256) void count_kernel(const int* __restrict__ ei,
                                                    const int* __restrict__ et,
                                                    int* __restrict__ counts,
                                                    int* __restrict__ rank) {
  int e = blockIdx.x * 256 + threadIdx.x;
  if (e >= Ee) return;
  int col = ei[Ee + e];
  int r = et[e];
  rank[e] = atomicAdd(&counts[r * Nn + col], 1);
}

__global__ __launch_bounds__(256) void scan1_kernel(const int* __restrict__ counts,
                                                    int* __restrict__ offs,
                                                    int* __restrict__ bsums, int n) {
  __shared__ int sh[256];
  int t = threadIdx.x;
  int base = blockIdx.x * 1024 + t * 4;
  int v0 = (base + 0 < n) ? counts[base + 0] : 0;
  int v1 = (base + 1 < n) ? counts[base + 1] : 0;
  int v2 = (base + 2 < n) ? counts[base + 2] : 0;
  int v3 = (base + 3 < n) ? counts[base + 3] : 0;
  int tot = v0 + v1 + v2 + v3;
  sh[t] = tot;
  __syncthreads();
  for (int off = 1; off < 256; off <<= 1) {
    int v = (t >= off) ? sh[t - off] : 0;
    __syncthreads();
    sh[t] += v;
    __syncthreads();
  }
  int run = sh[t] - tot;
  if (base + 0 < n) offs[base + 0] = run; run += v0;
  if (base + 1 < n) offs[base + 1] = run; run += v1;
  if (base + 2 < n) offs[base + 2] = run; run += v2;
  if (base + 3 < n) offs[base + 3] = run;
  if (t == 255) bsums[blockIdx.x] = sh[255];
}

__global__ __launch_bounds__(256) void scan_top_kernel(int* __restrict__ bsums, int nb) {
  __shared__ int sh[256];
  int t = threadIdx.x;
  int v = (t < nb) ? bsums[t] : 0;
  sh[t] = v;
  __syncthreads();
  for (int off = 1; off < 256; off <<= 1) {
    int x = (t >= off) ? sh[t - off] : 0;
    __syncthreads();
    sh[t] += x;
    __syncthreads();
  }
  if (t < nb) bsums[t] = sh[t] - v;
}

__global__ __launch_bounds__(256) void scan_add_kernel(int* __restrict__ offs,
                                                       const int* __restrict__ bsums,
                                                       int n) {
  int i = blockIdx.x * 256 + threadIdx.x;
  if (i > n) return;
  if (i == n) { offs[n] = Ee; return; }
  offs[i] += bsums[i >> 10];
}

__global__ __launch_bounds__(256) void fill_kernel(const int* __restrict__ ei,
                                                   const int* __restrict__ et,
                                                   const int* __restrict__ offs,
                                                   const int* __restrict__ rank,
                                                   int* __restrict__ srcs) {
  int e = blockIdx.x * 256 + threadIdx.x;
  if (e >= Ee) return;
  int row = ei[e];
  int col = ei[Ee + e];
  int r = et[e];
  int s = r * Nn + col;
  srcs[offs[s] + rank[e]] = row;   // atomic-free: rank captured in count pass
}

// ---------------------------------------------------------------------------
// Weight prep: Wt (bf16, n-major) [256][Kpad]; cols 0..191 = W[r], 192..255 = root
// ---------------------------------------------------------------------------
__global__ __launch_bounds__(256) void prep_wt_kernel(const float* __restrict__ W,
                                                      const float* __restrict__ root,
                                                      unsigned short* __restrict__ Wt,
                                                      int K, int Kpad) {
  int i = blockIdx.x * 256 + threadIdx.x;
  if (i >= 256 * Kpad) return;
  int c = i / Kpad, k = i % Kpad;
  float v = 0.f;
  if (k < K) {
    if (c < 192) {
      int r = c >> 6, h = c & 63;
      v = W[((long)r * K + k) * 64 + h];
    } else {
      v = root[k * 64 + (c - 192)];
    }
  }
  Wt[i] = f2bf(v);
}

// head weights: Wt_h [256][64] bf16 (rows 128..255 zero), biasH[128] fp32
__global__ __launch_bounds__(256) void prep_wth_kernel(const float* __restrict__ ew1,
                                                       const float* __restrict__ eb1,
                                                       unsigned short* __restrict__ Wth,
                                                       float* __restrict__ biasH) {
  int i = blockIdx.x * 256 + threadIdx.x;
  if (i < 128) biasH[i] = (i < 64) ? eb1[i] : 0.f;
  if (i >= 256 * 64) return;
  int c = i >> 6, k = i & 63;
  float v = 0.f;
  if (c < 64) v = ew1[k * 64 + c];
  else if (c < 128) v = ew1[(64 + k) * 64 + (c - 64)];
  Wth[i] = f2bf(v);
}

// ---------------------------------------------------------------------------
// bf16 MFMA GEMM v8: R9 schedule with BK=64 (half the K-steps).
//   tile 256x256, 1024 threads, 16 waves (4M x 4N). Grid 196 = 1 round,
//   1 block/CU -> no inter-block overlap; per-step barrier drains are the
//   cost, so HALVING step count (25 -> 13 for K=800) attacks it directly.
//   LDS 2 x 256 x 72 shorts = 73.7KB (free at 1 block/CU).
// ---------------------------------------------------------------------------
#define ASTR 72

#define PKBF(a, b) ((int)((unsigned)f2bf(a) | ((unsigned)f2bf(b) << 16)))

#define LOAD_A1(dst, kb)                                          \
  {                                                               \
    if (rowOK && (kb) + 4 <= K) {                                 \
      dst = *(const float4*)(aRow + (kb));                        \
    } else {                                                      \
      dst.x = (rowOK && (kb) + 0 < K) ? aRow[(kb) + 0] : 0.f;     \
      dst.y = (rowOK && (kb) + 1 < K) ? aRow[(kb) + 1] : 0.f;     \
      dst.z = (rowOK && (kb) + 2 < K) ? aRow[(kb) + 2] : 0.f;     \
      dst.w = (rowOK && (kb) + 3 < K) ? aRow[(kb) + 3] : 0.f;     \
    }                                                             \
  }
#define LOAD_A(k0)                                                \
  {                                                               \
    int kb = (k0) + ac;                                           \
    LOAD_A1(aP0, kb); LOAD_A1(aP1, kb + 4);                       \
    LOAD_A1(aP2, kb + 8); LOAD_A1(aP3, kb + 12);                  \
  }
#define LOAD_B(k0)                                                \
  {                                                               \
    const int4* srcp = (const int4*)(wRow + (k0));                \
    b0 = srcp[0]; b1 = srcp[1];                                   \
  }
#define STORE_TILE()                                              \
  {                                                               \
    int4 w0, w1;                                                  \
    w0.x = PKBF(aP0.x, aP0.y); w0.y = PKBF(aP0.z, aP0.w);         \
    w0.z = PKBF(aP1.x, aP1.y); w0.w = PKBF(aP1.z, aP1.w);         \
    w1.x = PKBF(aP2.x, aP2.y); w1.y = PKBF(aP2.z, aP2.w);         \
    w1.z = PKBF(aP3.x, aP3.y); w1.w = PKBF(aP3.z, aP3.w);         \
    int4* adst = (int4*)&As[ar * ASTR + ac];                      \
    adst[0] = w0; adst[1] = w1;                                   \
    int4* bdst = (int4*)&Bs[br * ASTR + bo];                      \
    bdst[0] = b0; bdst[1] = b1;                                   \
  }

__global__ __launch_bounds__(1024) void gemm_bf16_kernel(
    const float* __restrict__ Ag, const unsigned short* __restrict__ Wt,
    unsigned short* __restrict__ Cg, const float* __restrict__ bias,
    int M, int K, int Kpad, int Ncol) {
  __shared__ unsigned short As[256 * ASTR];
  __shared__ unsigned short Bs[256 * ASTR];
  int t = threadIdx.x;
  int lane = t & 63;
  int wid = t >> 6;              // 0..15
  int quad = lane >> 4;
  int l16 = lane & 15;
  int rowBase = blockIdx.x * 256;
  int mbase = (wid >> 2) * 64;   // 0,64,128,192
  int nbase = (wid & 3) * 64;    // 0,64,128,192

  floatx4 acc[4][4];
#pragma unroll
  for (int i = 0; i < 4; ++i)
#pragma unroll
    for (int j = 0; j < 4; ++j) acc[i][j] = (floatx4){0.f, 0.f, 0.f, 0.f};

  int ar = t >> 2;               // 0..255 : A row
  int ac = (t & 3) * 16;         // 0,16,32,48 : 16 fp32 per thread
  long gm = rowBase + ar;
  bool rowOK = (gm < M);
  const float* aRow = Ag + gm * (long)K;
  int br = t >> 2;               // 0..255 : B row
  int bo = (t & 3) * 16;         // 0,16,32,48 : 16 bf16 per thread
  const unsigned short* wRow = Wt + (size_t)br * Kpad + bo;

  float4 aP0, aP1, aP2, aP3;     // prefetched A (16 fp32)
  int4 b0, b1;                   // prefetched B (16 bf16)

  int KT = Kpad / 64;
  LOAD_A(0);
  LOAD_B(0);

  for (int kt = 0; kt < KT; ++kt) {
    STORE_TILE();
    __syncthreads();

    // issue next tile's global loads FIRST (overlap with ds_read + MFMA)
    if (kt + 1 < KT) {
      int k0n = (kt + 1) * 64;
      LOAD_A(k0n);
      LOAD_B(k0n);
    }

#pragma unroll
    for (int ks = 0; ks < 2; ++ks) {
      short8 af[4], bfr[4];
#pragma unroll
      for (int i = 0; i < 4; ++i)
        af[i] = *(const short8*)&As[(mbase + i * 16 + l16) * ASTR + ks * 32 + quad * 8];
#pragma unroll
      for (int j = 0; j < 4; ++j)
        bfr[j] = *(const short8*)&Bs[(nbase + j * 16 + l16) * ASTR + ks * 32 + quad * 8];
#pragma unroll
      for (int i = 0; i < 4; ++i)
#pragma unroll
        for (int j = 0; j < 4; ++j)
          acc[i][j] = __builtin_amdgcn_mfma_f32_16x16x32_bf16(af[i], bfr[j], acc[i][j], 0, 0, 0);
    }
    __syncthreads();
  }

#pragma unroll
  for (int j = 0; j < 4; ++j) {
    int gn = nbase + j * 16 + l16;
    if (gn >= Ncol) continue;
    float bv = bias ? bias[gn] : 0.f;
#pragma unroll
    for (int i = 0; i < 4; ++i) {
      int gm0 = rowBase + mbase + i * 16 + quad * 4;
#pragma unroll
      for (int r = 0; r < 4; ++r) {
        int gmm = gm0 + r;
        if (gmm < M) Cg[(long)gmm * Ncol + gn] = f2bf(acc[i][j][r] + bv);
      }
    }
  }
}

// ---------------------------------------------------------------------------
// Aggregation v4 (bf16 XR): one wave per dst; 8 slots x 8 edges; FLATTENED
// 3-relation edge loop. Per-edge relation picked by 2 compares; 1/cnt_r
// folded into FMA.
// ---------------------------------------------------------------------------
__global__ __launch_bounds__(256) void agg_kernel(const unsigned short* __restrict__ XR,
                                                  const int* __restrict__ offs,
                                                  const int* __restrict__ srcs,
                                                  const float* __restrict__ bias,
                                                  const float* __restrict__ lng,
                                                  const float* __restrict__ lnb,
                                                  float* __restrict__ out, int mode) {
  int lane = threadIdx.x & 63;
  int wid = threadIdx.x >> 6;
  int slot = lane >> 3;     // 0..7 : edge slot
  int l8 = lane & 7;        // h-chunk: h = l8*8 .. l8*8+7
  int dst = blockIdx.x * 4 + wid;
  if (dst >= Nn) return;

  int b0 = offs[dst],          e0 = offs[dst + 1];
  int b1 = offs[Nn + dst],     e1 = offs[Nn + dst + 1];
  int b2 = offs[2 * Nn + dst], e2 = offs[2 * Nn + dst + 1];
  int c0 = e0 - b0, c1 = e1 - b1, c2 = e2 - b2;
  int c01 = c0 + c1;
  int tot = c01 + c2;
  float inv0 = (c0 > 0) ? 1.f / (float)c0 : 0.f;
  float inv1 = (c1 > 0) ? 1.f / (float)c1 : 0.f;
  float inv2 = (c2 > 0) ? 1.f / (float)c2 : 0.f;

  float a0 = 0.f, a1 = 0.f, a2 = 0.f, a3 = 0.f;
  float a4 = 0.f, a5 = 0.f, a6 = 0.f, a7 = 0.f;
  for (int i = slot; i < tot; i += 8) {
    int e; float inv; int roff;
    if (i < c0)       { e = b0 + i;         inv = inv0; roff = 0; }
    else if (i < c01) { e = b1 + (i - c0);  inv = inv1; roff = 64; }
    else              { e = b2 + (i - c01); inv = inv2; roff = 128; }
    int src = srcs[e];
    int4 v = *(const int4*)&XR[(long)src * 256 + roff + l8 * 8];
    unsigned u0 = (unsigned)v.x, u1 = (unsigned)v.y;
    unsigned u2 = (unsigned)v.z, u3 = (unsigned)v.w;
    a0 = fmaf(__int_as_float(u0 << 16), inv, a0);
    a1 = fmaf(__int_as_float(u0 & 0xffff0000u), inv, a1);
    a2 = fmaf(__int_as_float(u1 << 16), inv, a2);
    a3 = fmaf(__int_as_float(u1 & 0xffff0000u), inv, a3);
    a4 = fmaf(__int_as_float(u2 << 16), inv, a4);
    a5 = fmaf(__int_as_float(u2 & 0xffff0000u), inv, a5);
    a6 = fmaf(__int_as_float(u3 << 16), inv, a6);
    a7 = fmaf(__int_as_float(u3 & 0xffff0000u), inv, a7);
  }
  // cross-slot reduction (lanes differing in bits 3..5)
#pragma unroll
  for (int m = 8; m < 64; m <<= 1) {
    a0 += __shfl_xor(a0, m, 64); a1 += __shfl_xor(a1, m, 64);
    a2 += __shfl_xor(a2, m, 64); a3 += __shfl_xor(a3, m, 64);
    a4 += __shfl_xor(a4, m, 64); a5 += __shfl_xor(a5, m, 64);
    a6 += __shfl_xor(a6, m, 64); a7 += __shfl_xor(a7, m, 64);
  }

  int4 rt = *(const int4*)&XR[(long)dst * 256 + 192 + l8 * 8];
  unsigned r0 = (unsigned)rt.x, r1 = (unsigned)rt.y;
  unsigned r2 = (unsigned)rt.z, r3 = (unsigned)rt.w;
  float4 bv0 = *(const float4*)&bias[l8 * 8];
  float4 bv1 = *(const float4*)&bias[l8 * 8 + 4];
  float t0 = a0 + __int_as_float(r0 << 16) + bv0.x;
  float t1 = a1 + __int_as_float(r0 & 0xffff0000u) + bv0.y;
  float t2 = a2 + __int_as_float(r1 << 16) + bv0.z;
  float t3 = a3 + __int_as_float(r1 & 0xffff0000u) + bv0.w;
  float t4 = a4 + __int_as_float(r2 << 16) + bv1.x;
  float t5 = a5 + __int_as_float(r2 & 0xffff0000u) + bv1.y;
  float t6 = a6 + __int_as_float(r3 << 16) + bv1.z;
  float t7 = a7 + __int_as_float(r3 & 0xffff0000u) + bv1.w;

  if (mode == 0) {
    if (slot == 0) {
      float4 o0, o1;
      o0.x = fmaxf(t0, 0.f); o0.y = fmaxf(t1, 0.f);
      o0.z = fmaxf(t2, 0.f); o0.w = fmaxf(t3, 0.f);
      o1.x = fmaxf(t4, 0.f); o1.y = fmaxf(t5, 0.f);
      o1.z = fmaxf(t6, 0.f); o1.w = fmaxf(t7, 0.f);
      *(float4*)&out[(long)dst * 64 + l8 * 8] = o0;
      *(float4*)&out[(long)dst * 64 + l8 * 8 + 4] = o1;
    }
  } else {
    float s = t0 + t1 + t2 + t3 + t4 + t5 + t6 + t7;
    s += __shfl_xor(s, 1, 64); s += __shfl_xor(s, 2, 64); s += __shfl_xor(s, 4, 64);
    float mu = s * (1.f / 64.f);
    float d0 = t0 - mu, d1 = t1 - mu, d2 = t2 - mu, d3 = t3 - mu;
    float d4 = t4 - mu, d5 = t5 - mu, d6 = t6 - mu, d7 = t7 - mu;
    float vv = d0 * d0 + d1 * d1 + d2 * d2 + d3 * d3 +
               d4 * d4 + d5 * d5 + d6 * d6 + d7 * d7;
    vv += __shfl_xor(vv, 1, 64); vv += __shfl_xor(vv, 2, 64); vv += __shfl_xor(vv, 4, 64);
    float rstd = rsqrtf(vv * (1.f / 64.f) + 1e-5f);
    if (slot == 0) {
      float4 g0 = *(const float4*)&lng[l8 * 8];
      float4 g1 = *(const float4*)&lng[l8 * 8 + 4];
      float4 c0v = *(const float4*)&lnb[l8 * 8];
      float4 c1v = *(const float4*)&lnb[l8 * 8 + 4];
      float4 o0, o1;
      o0.x = d0 * rstd * g0.x + c0v.x;
      o0.y = d1 * rstd * g0.y + c0v.y;
      o0.z = d2 * rstd * g0.z + c0v.z;
      o0.w = d3 * rstd * g0.w + c0v.w;
      o1.x = d4 * rstd * g1.x + c1v.x;
      o1.y = d5 * rstd * g1.y + c1v.y;
      o1.z = d6 * rstd * g1.z + c1v.z;
      o1.w = d7 * rstd * g1.w + c1v.w;
      *(float4*)&out[(long)dst * 64 + l8 * 8] = o0;
      *(float4*)&out[(long)dst * 64 + l8 * 8 + 4] = o1;
    }
  }
}

// ---------------------------------------------------------------------------
// Edge head v2: 4 lanes per edge, each lane covers 16 consecutive h
// (2 int4 at offset sub*16 shorts); 2-level shfl; sublane 0 writes.
// ---------------------------------------------------------------------------
__global__ __launch_bounds__(256) void edge_head_kernel(const unsigned short* __restrict__ AB,
                                                        const int* __restrict__ ei,
                                                        const float* __restrict__ ew2,
                                                        const float* __restrict__ eb2,
                                                        float* __restrict__ out) {
  int t = threadIdx.x;
  long e = (long)blockIdx.x * 64 + (t >> 2);
  if (e >= Ee) return;
  int sub = t & 3;
  int row = ei[e];
  int col = ei[Ee + e];
  const int4* pa = (const int4*)&AB[(long)row * 128 + sub * 16];
  const int4* pb = (const int4*)&AB[(long)col * 128 + 64 + sub * 16];
  float acc0 = 0.f, acc1 = 0.f, acc2 = 0.f;
#pragma unroll
  for (int qq = 0; qq < 2; ++qq) {
    int4 av = pa[qq];
    int4 bv = pb[qq];
    const int* ad = (const int*)&av;
    const int* bd = (const int*)&bv;
#pragma unroll
    for (int d = 0; d < 4; ++d) {
      int A = ad[d], B = bd[d];
      float a0 = __int_as_float(A << 16);
      float a1 = __int_as_float(A & 0xffff0000);
      float b0 = __int_as_float(B << 16);
      float b1 = __int_as_float(B & 0xffff0000);
      float e0 = fmaxf(a0 + b0, 0.f);
      float e1 = fmaxf(a1 + b1, 0.f);
      int h = sub * 16 + qq * 8 + d * 2;
      acc0 = fmaf(e0, ew2[h * 3 + 0], acc0);
      acc1 = fmaf(e0, ew2[h * 3 + 1], acc1);
      acc2 = fmaf(e0, ew2[h * 3 + 2], acc2);
      acc0 = fmaf(e1, ew2[h * 3 + 3], acc0);
      acc1 = fmaf(e1, ew2[h * 3 + 4], acc1);
      acc2 = fmaf(e1, ew2[h * 3 + 5], acc2);
    }
  }
  acc0 += __shfl_xor(acc0, 1, 64); acc0 += __shfl_xor(acc0, 2, 64);
  acc1 += __shfl_xor(acc1, 1, 64); acc1 += __shfl_xor(acc1, 2, 64);
  acc2 += __shfl_xor(acc2, 1, 64); acc2 += __shfl_xor(acc2, 2, 64);
  if (sub == 0) {
    float l0 = acc0 + eb2[0], l1 = acc1 + eb2[1], l2 = acc2 + eb2[2];
    float mx = fmaxf(l0, fmaxf(l1, l2));
    float ls = mx + logf(expf(l0 - mx) + expf(l1 - mx) + expf(l2 - mx));
    out[e * 3 + 0] = l0 - ls;
    out[e * 3 + 1] = l1 - ls;
    out[e * 3 + 2] = l2 - ls;
  }
}

// ---------------------------------------------------------------------------
// Node head: one thread per node (x3 fp32).
// ---------------------------------------------------------------------------
__global__ __launch_bounds__(256) void node_head_kernel(const float* __restrict__ x3,
                                                        const float* __restrict__ nw1,
                                                        const float* __restrict__ nb1,
                                                        const float* __restrict__ nw2,
                                                        const float* __restrict__ nb2,
                                                        float* __restrict__ out) {
  __shared__ float w1s[64 * 32];
  __shared__ float w2s[64];
  for (int i = threadIdx.x; i < 2048; i += 256) w1s[i] = nw1[i];
  if (threadIdx.x < 64) w2s[threadIdx.x] = nw2[threadIdx.x];
  __syncthreads();
  int n = blockIdx.x * 256 + threadIdx.x;
  if (n >= Nn) return;
  float acc[32];
#pragma unroll
  for (int c = 0; c < 32; ++c) acc[c] = nb1[c];
  for (int k = 0; k < 64; ++k) {
    float xv = x3[(long)n * 64 + k];
#pragma unroll
    for (int c = 0; c < 32; ++c) acc[c] += xv * w1s[k * 32 + c];
  }
  float l0 = nb2[0], l1 = nb2[1];
#pragma unroll
  for (int c = 0; c < 32; ++c) {
    float h = fmaxf(acc[c], 0.f);
    l0 += h * w2s[c * 2 + 0];
    l1 += h * w2s[c * 2 + 1];
  }
  float mx = fmaxf(l0, l1);
  float ls = mx + logf(expf(l0 - mx) + expf(l1 - mx));
  out[(long)3 * Ee + (long)n * 2 + 0] = l0 - ls;
  out[(long)3 * Ee + (long)n * 2 + 1] = l1 - ls;
}

// ---------------------------------------------------------------------------
extern "C" void kernel_launch(void* const* d_in, const int* in_sizes, int n_in,
                              void* d_out, int out_size, void* d_ws, size_t ws_size,
                              hipStream_t stream) {
  const float* x = (const float*)d_in[0];
  const int* ei = (const int*)d_in[1];
  const int* et = (const int*)d_in[2];
  const float* W1 = (const float*)d_in[3];
  const float* root1 = (const float*)d_in[4];
  const float* b1 = (const float*)d_in[5];
  const float* W2 = (const float*)d_in[6];
  const float* root2 = (const float*)d_in[7];
  const float* b2 = (const float*)d_in[8];
  const float* W3 = (const float*)d_in[9];
  const float* root3 = (const float*)d_in[10];
  const float* b3 = (const float*)d_in[11];
  const float* lng = (const float*)d_in[12];
  const float* lnb = (const float*)d_in[13];
  const float* ew1 = (const float*)d_in[14];
  const float* eb1 = (const float*)d_in[15];
  const float* ew2 = (const float*)d_in[16];
  const float* eb2 = (const float*)d_in[17];
  const float* nw1 = (const float*)d_in[18];
  const float* nb1 = (const float*)d_in[19];
  const float* nw2 = (const float*)d_in[20];
  const float* nb2 = (const float*)d_in[21];
  float* out = (float*)d_out;

  char* p = (char*)d_ws;
  size_t off = 0;
  auto alloc = [&](size_t bytes) {
    void* r = p + off;
    off += (bytes + 255) & ~(size_t)255;
    return r;
  };
  // Workspace kept within the proven footprint: rank/counts ALIAS xA/xB
  // (rank & counts are dead before xA/xB's first writes in layer-1/2 agg).
  unsigned short* XR = (unsigned short*)alloc((size_t)Nn * 256 * 2);  // bf16; also AB
  float* xA = (float*)alloc((size_t)Nn * 64 * 4);
  float* xB = (float*)alloc((size_t)Nn * 64 * 4);
  int* srcs = (int*)alloc((size_t)Ee * 4);
  int* offs = (int*)alloc((size_t)(RN + 1) * 4);
  int* bsums = (int*)alloc(1024);
  unsigned short* Wt1 = (unsigned short*)alloc((size_t)256 * KPAD1 * 2);
  unsigned short* Wt2 = (unsigned short*)alloc((size_t)256 * 64 * 2);
  unsigned short* Wt3 = (unsigned short*)alloc((size_t)256 * 64 * 2);
  unsigned short* Wth = (unsigned short*)alloc((size_t)256 * 64 * 2);
  float* biasH = (float*)alloc(128 * 4);
  int* rank = (int*)xA;     // Ee*4 = 6.4MB <= 12.8MB; dead before xA written
  int* counts = (int*)xB;   // RN*4 = 0.6MB <= 12.8MB; dead before xB written

  int nb = (RN + 1023) / 1024;  // 147

  // --- CSR build (rank captured in count pass; fill is atomic-free) ---
  hipMemsetAsync(counts, 0, (size_t)RN * 4, stream);
  count_kernel<<<(Ee + 255) / 256, 256, 0, stream>>>(ei, et, counts, rank);
  scan1_kernel<<<nb, 256, 0, stream>>>(counts, offs, bsums, RN);
  scan_top_kernel<<<1, 256, 0, stream>>>(bsums, nb);
  scan_add_kernel<<<(RN + 256) / 256 + 1, 256, 0, stream>>>(offs, bsums, RN);
  fill_kernel<<<(Ee + 255) / 256, 256, 0, stream>>>(ei, et, offs, rank, srcs);

  // --- weight prep (bf16 transposed) ---
  prep_wt_kernel<<<(256 * KPAD1 + 255) / 256, 256, 0, stream>>>(W1, root1, Wt1, FIN, KPAD1);
  prep_wt_kernel<<<(256 * 64 + 255) / 256, 256, 0, stream>>>(W2, root2, Wt2, 64, 64);
  prep_wt_kernel<<<(256 * 64 + 255) / 256, 256, 0, stream>>>(W3, root3, Wt3, 64, 64);
  prep_wth_kernel<<<(256 * 64 + 255) / 256, 256, 0, stream>>>(ew1, eb1, Wth, biasH);

  int gemmBlocks = (Nn + 255) / 256;  // 196
  int aggBlocks = (Nn + 3) / 4;

  // --- layer 1 ---
  gemm_bf16_kernel<<<gemmBlocks, 1024, 0, stream>>>(x, Wt1, XR, nullptr, Nn, FIN, KPAD1, 256);
  agg_kernel<<<aggBlocks, 256, 0, stream>>>(XR, offs, srcs, b1, nullptr, nullptr, xA, 0);
  // --- layer 2 ---
  gemm_bf16_kernel<<<gemmBlocks, 1024, 0, stream>>>(xA, Wt2, XR, nullptr, Nn, 64, 64, 256);
  agg_kernel<<<aggBlocks, 256, 0, stream>>>(XR, offs, srcs, b2, nullptr, nullptr, xB, 0);
  // --- layer 3 + layernorm ---
  gemm_bf16_kernel<<<gemmBlocks, 1024, 0, stream>>>(xB, Wt3, XR, nullptr, Nn, 64, 64, 256);
  agg_kernel<<<aggBlocks, 256, 0, stream>>>(XR, offs, srcs, b3, lng, lnb, xA, 1);

  // --- heads ---
  gemm_bf16_kernel<<<gemmBlocks, 1024, 0, stream>>>(xA, Wth, XR, biasH, Nn, 64, 64, 128);
  edge_head_kernel<<<(Ee + 63) / 64, 256, 0, stream>>>(XR, ei, ew2, eb2, out);
  node_head_kernel<<<(Nn + 255) / 256, 256, 0, stream>>>(xA, nw1, nb1, nw2, nb2, out);
}

// Round 13
// 679.020 us; speedup vs baseline: 1.0913x; 1.0913x over previous
//
#include <hip/hip_runtime.h>
#include <hip/hip_bf16.h>
#include <math.h>

#define Nn 50000
#define Ee 1600000
#define RR 3
#define RN (RR * Nn)
#define FIN 770
#define KPAD1 800

typedef __attribute__((ext_vector_type(8))) short short8;
typedef __attribute__((ext_vector_type(4))) float floatx4;

static __device__ __forceinline__ unsigned short f2bf(float v) {
  __hip_bfloat16 h = __float2bfloat16(v);
  return *(unsigned short*)&h;
}

// ---------------------------------------------------------------------------
// CSR build: count (atomic, returns rank) -> exclusive scan -> atomic-free fill
// ---------------------------------------------------------------------------
__global__ __launch_bounds__(256) void count_kernel(const int* __restrict__ ei,
                                                    const int* __restrict__ et,
                                                    int* __restrict__ counts,
                                                    int* __restrict__ rank) {
  int e = blockIdx.x * 256 + threadIdx.x;
  if (e >= Ee) return;
  int col = ei[Ee + e];
  int r = et[e];
  rank[e] = atomicAdd(&counts[r * Nn + col], 1);
}

__global__ __launch_bounds__(256) void scan1_kernel(const int* __restrict__ counts,
                                                    int* __restrict__ offs,
                                                    int* __restrict__ bsums, int n) {
  __shared__ int sh[256];
  int t = threadIdx.x;
  int base = blockIdx.x * 1024 + t * 4;
  int v0 = (base + 0 < n) ? counts[base + 0] : 0;
  int v1 = (base + 1 < n) ? counts[base + 1] : 0;
  int v2 = (base + 2 < n) ? counts[base + 2] : 0;
  int v3 = (base + 3 < n) ? counts[base + 3] : 0;
  int tot = v0 + v1 + v2 + v3;
  sh[t] = tot;
  __syncthreads();
  for (int off = 1; off < 256; off <<= 1) {
    int v = (t >= off) ? sh[t - off] : 0;
    __syncthreads();
    sh[t] += v;
    __syncthreads();
  }
  int run = sh[t] - tot;
  if (base + 0 < n) offs[base + 0] = run; run += v0;
  if (base + 1 < n) offs[base + 1] = run; run += v1;
  if (base + 2 < n) offs[base + 2] = run; run += v2;
  if (base + 3 < n) offs[base + 3] = run;
  if (t == 255) bsums[blockIdx.x] = sh[255];
}

__global__ __launch_bounds__(256) void scan_top_kernel(int* __restrict__ bsums, int nb) {
  __shared__ int sh[256];
  int t = threadIdx.x;
  int v = (t < nb) ? bsums[t] : 0;
  sh[t] = v;
  __syncthreads();
  for (int off = 1; off < 256; off <<= 1) {
    int x = (t >= off) ? sh[t - off] : 0;
    __syncthreads();
    sh[t] += x;
    __syncthreads();
  }
  if (t < nb) bsums[t] = sh[t] - v;
}

__global__ __launch_bounds__(256) void scan_add_kernel(int* __restrict__ offs,
                                                       const int* __restrict__ bsums,
                                                       int n) {
  int i = blockIdx.x * 256 + threadIdx.x;
  if (i > n) return;
  if (i == n) { offs[n] = Ee; return; }
  offs[i] += bsums[i >> 10];
}

__global__ __launch_bounds__(256) void fill_kernel(const int* __restrict__ ei,
                                                   const int* __restrict__ et,
                                                   const int* __restrict__ offs,
                                                   const int* __restrict__ rank,
                                                   int* __restrict__ srcs) {
  int e = blockIdx.x * 256 + threadIdx.x;
  if (e >= Ee) return;
  int row = ei[e];
  int col = ei[Ee + e];
  int r = et[e];
  int s = r * Nn + col;
  srcs[offs[s] + rank[e]] = row;   // atomic-free: rank captured in count pass
}

// ---------------------------------------------------------------------------
// Weight prep: Wt (bf16, n-major) [256][Kpad]; cols 0..191 = W[r], 192..255 = root
// ---------------------------------------------------------------------------
__global__ __launch_bounds__(256) void prep_wt_kernel(const float* __restrict__ W,
                                                      const float* __restrict__ root,
                                                      unsigned short* __restrict__ Wt,
                                                      int K, int Kpad) {
  int i = blockIdx.x * 256 + threadIdx.x;
  if (i >= 256 * Kpad) return;
  int c = i / Kpad, k = i % Kpad;
  float v = 0.f;
  if (k < K) {
    if (c < 192) {
      int r = c >> 6, h = c & 63;
      v = W[((long)r * K + k) * 64 + h];
    } else {
      v = root[k * 64 + (c - 192)];
    }
  }
  Wt[i] = f2bf(v);
}

// head weights: Wt_h [256][64] bf16 (rows 128..255 zero), biasH[128] fp32
__global__ __launch_bounds__(256) void prep_wth_kernel(const float* __restrict__ ew1,
                                                       const float* __restrict__ eb1,
                                                       unsigned short* __restrict__ Wth,
                                                       float* __restrict__ biasH) {
  int i = blockIdx.x * 256 + threadIdx.x;
  if (i < 128) biasH[i] = (i < 64) ? eb1[i] : 0.f;
  if (i >= 256 * 64) return;
  int c = i >> 6, k = i & 63;
  float v = 0.f;
  if (c < 64) v = ew1[k * 64 + c];
  else if (c < 128) v = ew1[(64 + k) * 64 + (c - 64)];
  Wth[i] = f2bf(v);
}

// ---------------------------------------------------------------------------
// bf16 MFMA GEMM v6 (R9/R11-proven; BK=32. R12's BK=64 regressed 95->132us:
// per-step cost scales with staged bytes, not barrier count — config is a
// verified local optimum of this structure).
//   tile 256x256, 1024 threads, 16 waves (4M x 4N), grid 196 = 1 round.
// ---------------------------------------------------------------------------
#define ASTR 40
#define BSTR 40

#define LOAD_A_FULL(k0)                                        \
  {                                                            \
    const float* ap = aRow + (k0) + ac;                        \
    a01 = *(const float4*)(ap + 0);                            \
    a23 = *(const float4*)(ap + 4);                            \
  }
#define LOAD_A_MASK(k0)                                        \
  {                                                            \
    int kb = (k0) + ac;                                        \
    a01.x = (rowOK && kb + 0 < K) ? aRow[kb + 0] : 0.f;        \
    a01.y = (rowOK && kb + 1 < K) ? aRow[kb + 1] : 0.f;        \
    a01.z = (rowOK && kb + 2 < K) ? aRow[kb + 2] : 0.f;        \
    a01.w = (rowOK && kb + 3 < K) ? aRow[kb + 3] : 0.f;        \
    a23.x = (rowOK && kb + 4 < K) ? aRow[kb + 4] : 0.f;        \
    a23.y = (rowOK && kb + 5 < K) ? aRow[kb + 5] : 0.f;        \
    a23.z = (rowOK && kb + 6 < K) ? aRow[kb + 6] : 0.f;        \
    a23.w = (rowOK && kb + 7 < K) ? aRow[kb + 7] : 0.f;        \
  }
#define LOAD_A(k0)                                             \
  if (rowOK && (k0) + 32 <= K) LOAD_A_FULL(k0) else LOAD_A_MASK(k0)
#define LOAD_B(k0)                                             \
  {                                                            \
    b0 = *(const int4*)(wRow + (k0));                          \
  }
#define STORE_TILE()                                                          \
  {                                                                           \
    __hip_bfloat162* adst = (__hip_bfloat162*)&As[ar * ASTR + ac];            \
    adst[0] = __hip_bfloat162(__float2bfloat16(a01.x), __float2bfloat16(a01.y)); \
    adst[1] = __hip_bfloat162(__float2bfloat16(a01.z), __float2bfloat16(a01.w)); \
    adst[2] = __hip_bfloat162(__float2bfloat16(a23.x), __float2bfloat16(a23.y)); \
    adst[3] = __hip_bfloat162(__float2bfloat16(a23.z), __float2bfloat16(a23.w)); \
    *(int4*)&Bs[br * BSTR + bo] = b0;                                         \
  }

__global__ __launch_bounds__(1024) void gemm_bf16_kernel(
    const float* __restrict__ Ag, const unsigned short* __restrict__ Wt,
    unsigned short* __restrict__ Cg, const float* __restrict__ bias,
    int M, int K, int Kpad, int Ncol) {
  __shared__ unsigned short As[256 * ASTR];
  __shared__ unsigned short Bs[256 * BSTR];
  int t = threadIdx.x;
  int lane = t & 63;
  int wid = t >> 6;              // 0..15
  int quad = lane >> 4;
  int l16 = lane & 15;
  int rowBase = blockIdx.x * 256;
  int mbase = (wid >> 2) * 64;   // 0,64,128,192
  int nbase = (wid & 3) * 64;    // 0,64,128,192

  floatx4 acc[4][4];
#pragma unroll
  for (int i = 0; i < 4; ++i)
#pragma unroll
    for (int j = 0; j < 4; ++j) acc[i][j] = (floatx4){0.f, 0.f, 0.f, 0.f};

  int ar = t >> 2;               // 0..255 : A row
  int ac = (t & 3) * 8;          // 0..24  : 8 fp32 per thread
  long gm = rowBase + ar;
  bool rowOK = (gm < M);
  const float* aRow = Ag + gm * (long)K;
  int br = t >> 2;               // 0..255 : B row
  int bo = (t & 3) * 8;          // 0..24  : 8 bf16 per thread
  const unsigned short* wRow = Wt + (size_t)br * Kpad + bo;

  float4 a01, a23;   // prefetched A (8 fp32)
  int4 b0;           // prefetched B (8 bf16)

  int KT = Kpad / 32;
  LOAD_A(0);
  LOAD_B(0);

  for (int kt = 0; kt < KT; ++kt) {
    STORE_TILE();
    __syncthreads();

    // issue next tile's global loads FIRST (overlap with ds_read + MFMA)
    if (kt + 1 < KT) {
      int k0n = (kt + 1) * 32;
      LOAD_A(k0n);
      LOAD_B(k0n);
    }

    short8 af[4], bfr[4];
#pragma unroll
    for (int i = 0; i < 4; ++i)
      af[i] = *(const short8*)&As[(mbase + i * 16 + l16) * ASTR + quad * 8];
#pragma unroll
    for (int j = 0; j < 4; ++j)
      bfr[j] = *(const short8*)&Bs[(nbase + j * 16 + l16) * BSTR + quad * 8];

#pragma unroll
    for (int i = 0; i < 4; ++i)
#pragma unroll
      for (int j = 0; j < 4; ++j)
        acc[i][j] = __builtin_amdgcn_mfma_f32_16x16x32_bf16(af[i], bfr[j], acc[i][j], 0, 0, 0);
    __syncthreads();
  }

#pragma unroll
  for (int j = 0; j < 4; ++j) {
    int gn = nbase + j * 16 + l16;
    if (gn >= Ncol) continue;
    float bv = bias ? bias[gn] : 0.f;
#pragma unroll
    for (int i = 0; i < 4; ++i) {
      int gm0 = rowBase + mbase + i * 16 + quad * 4;
#pragma unroll
      for (int r = 0; r < 4; ++r) {
        int gmm = gm0 + r;
        if (gmm < M) Cg[(long)gmm * Ncol + gn] = f2bf(acc[i][j][r] + bv);
      }
    }
  }
}

// ---------------------------------------------------------------------------
// Aggregation v4 (bf16 XR): one wave per dst; 8 slots x 8 edges; FLATTENED
// 3-relation edge loop. Per-edge relation picked by 2 compares; 1/cnt_r
// folded into FMA.
// ---------------------------------------------------------------------------
__global__ __launch_bounds__(256) void agg_kernel(const unsigned short* __restrict__ XR,
                                                  const int* __restrict__ offs,
                                                  const int* __restrict__ srcs,
                                                  const float* __restrict__ bias,
                                                  const float* __restrict__ lng,
                                                  const float* __restrict__ lnb,
                                                  float* __restrict__ out, int mode) {
  int lane = threadIdx.x & 63;
  int wid = threadIdx.x >> 6;
  int slot = lane >> 3;     // 0..7 : edge slot
  int l8 = lane & 7;        // h-chunk: h = l8*8 .. l8*8+7
  int dst = blockIdx.x * 4 + wid;
  if (dst >= Nn) return;

  int b0 = offs[dst],          e0 = offs[dst + 1];
  int b1 = offs[Nn + dst],     e1 = offs[Nn + dst + 1];
  int b2 = offs[2 * Nn + dst], e2 = offs[2 * Nn + dst + 1];
  int c0 = e0 - b0, c1 = e1 - b1, c2 = e2 - b2;
  int c01 = c0 + c1;
  int tot = c01 + c2;
  float inv0 = (c0 > 0) ? 1.f / (float)c0 : 0.f;
  float inv1 = (c1 > 0) ? 1.f / (float)c1 : 0.f;
  float inv2 = (c2 > 0) ? 1.f / (float)c2 : 0.f;

  float a0 = 0.f, a1 = 0.f, a2 = 0.f, a3 = 0.f;
  float a4 = 0.f, a5 = 0.f, a6 = 0.f, a7 = 0.f;
  for (int i = slot; i < tot; i += 8) {
    int e; float inv; int roff;
    if (i < c0)       { e = b0 + i;         inv = inv0; roff = 0; }
    else if (i < c01) { e = b1 + (i - c0);  inv = inv1; roff = 64; }
    else              { e = b2 + (i - c01); inv = inv2; roff = 128; }
    int src = srcs[e];
    int4 v = *(const int4*)&XR[(long)src * 256 + roff + l8 * 8];
    unsigned u0 = (unsigned)v.x, u1 = (unsigned)v.y;
    unsigned u2 = (unsigned)v.z, u3 = (unsigned)v.w;
    a0 = fmaf(__int_as_float(u0 << 16), inv, a0);
    a1 = fmaf(__int_as_float(u0 & 0xffff0000u), inv, a1);
    a2 = fmaf(__int_as_float(u1 << 16), inv, a2);
    a3 = fmaf(__int_as_float(u1 & 0xffff0000u), inv, a3);
    a4 = fmaf(__int_as_float(u2 << 16), inv, a4);
    a5 = fmaf(__int_as_float(u2 & 0xffff0000u), inv, a5);
    a6 = fmaf(__int_as_float(u3 << 16), inv, a6);
    a7 = fmaf(__int_as_float(u3 & 0xffff0000u), inv, a7);
  }
  // cross-slot reduction (lanes differing in bits 3..5)
#pragma unroll
  for (int m = 8; m < 64; m <<= 1) {
    a0 += __shfl_xor(a0, m, 64); a1 += __shfl_xor(a1, m, 64);
    a2 += __shfl_xor(a2, m, 64); a3 += __shfl_xor(a3, m, 64);
    a4 += __shfl_xor(a4, m, 64); a5 += __shfl_xor(a5, m, 64);
    a6 += __shfl_xor(a6, m, 64); a7 += __shfl_xor(a7, m, 64);
  }

  int4 rt = *(const int4*)&XR[(long)dst * 256 + 192 + l8 * 8];
  unsigned r0 = (unsigned)rt.x, r1 = (unsigned)rt.y;
  unsigned r2 = (unsigned)rt.z, r3 = (unsigned)rt.w;
  float4 bv0 = *(const float4*)&bias[l8 * 8];
  float4 bv1 = *(const float4*)&bias[l8 * 8 + 4];
  float t0 = a0 + __int_as_float(r0 << 16) + bv0.x;
  float t1 = a1 + __int_as_float(r0 & 0xffff0000u) + bv0.y;
  float t2 = a2 + __int_as_float(r1 << 16) + bv0.z;
  float t3 = a3 + __int_as_float(r1 & 0xffff0000u) + bv0.w;
  float t4 = a4 + __int_as_float(r2 << 16) + bv1.x;
  float t5 = a5 + __int_as_float(r2 & 0xffff0000u) + bv1.y;
  float t6 = a6 + __int_as_float(r3 << 16) + bv1.z;
  float t7 = a7 + __int_as_float(r3 & 0xffff0000u) + bv1.w;

  if (mode == 0) {
    if (slot == 0) {
      float4 o0, o1;
      o0.x = fmaxf(t0, 0.f); o0.y = fmaxf(t1, 0.f);
      o0.z = fmaxf(t2, 0.f); o0.w = fmaxf(t3, 0.f);
      o1.x = fmaxf(t4, 0.f); o1.y = fmaxf(t5, 0.f);
      o1.z = fmaxf(t6, 0.f); o1.w = fmaxf(t7, 0.f);
      *(float4*)&out[(long)dst * 64 + l8 * 8] = o0;
      *(float4*)&out[(long)dst * 64 + l8 * 8 + 4] = o1;
    }
  } else {
    float s = t0 + t1 + t2 + t3 + t4 + t5 + t6 + t7;
    s += __shfl_xor(s, 1, 64); s += __shfl_xor(s, 2, 64); s += __shfl_xor(s, 4, 64);
    float mu = s * (1.f / 64.f);
    float d0 = t0 - mu, d1 = t1 - mu, d2 = t2 - mu, d3 = t3 - mu;
    float d4 = t4 - mu, d5 = t5 - mu, d6 = t6 - mu, d7 = t7 - mu;
    float vv = d0 * d0 + d1 * d1 + d2 * d2 + d3 * d3 +
               d4 * d4 + d5 * d5 + d6 * d6 + d7 * d7;
    vv += __shfl_xor(vv, 1, 64); vv += __shfl_xor(vv, 2, 64); vv += __shfl_xor(vv, 4, 64);
    float rstd = rsqrtf(vv * (1.f / 64.f) + 1e-5f);
    if (slot == 0) {
      float4 g0 = *(const float4*)&lng[l8 * 8];
      float4 g1 = *(const float4*)&lng[l8 * 8 + 4];
      float4 c0v = *(const float4*)&lnb[l8 * 8];
      float4 c1v = *(const float4*)&lnb[l8 * 8 + 4];
      float4 o0, o1;
      o0.x = d0 * rstd * g0.x + c0v.x;
      o0.y = d1 * rstd * g0.y + c0v.y;
      o0.z = d2 * rstd * g0.z + c0v.z;
      o0.w = d3 * rstd * g0.w + c0v.w;
      o1.x = d4 * rstd * g1.x + c1v.x;
      o1.y = d5 * rstd * g1.y + c1v.y;
      o1.z = d6 * rstd * g1.z + c1v.z;
      o1.w = d7 * rstd * g1.w + c1v.w;
      *(float4*)&out[(long)dst * 64 + l8 * 8] = o0;
      *(float4*)&out[(long)dst * 64 + l8 * 8 + 4] = o1;
    }
  }
}

// ---------------------------------------------------------------------------
// Edge head v3: 8 lanes per edge, each lane exactly ONE int4 per endpoint
// (8 h values, 24 FMAs); 3-level shfl; sublane 0 does log-softmax + write.
// Halves the per-edge serial chain vs v2 and doubles edge concurrency.
// ---------------------------------------------------------------------------
__global__ __launch_bounds__(256) void edge_head_kernel(const unsigned short* __restrict__ AB,
                                                        const int* __restrict__ ei,
                                                        const float* __restrict__ ew2,
                                                        const float* __restrict__ eb2,
                                                        float* __restrict__ out) {
  int t = threadIdx.x;
  long e = (long)blockIdx.x * 32 + (t >> 3);
  if (e >= Ee) return;
  int sub = t & 7;
  int row = ei[e];
  int col = ei[Ee + e];
  int4 av = *(const int4*)&AB[(long)row * 128 + sub * 8];
  int4 bv = *(const int4*)&AB[(long)col * 128 + 64 + sub * 8];
  float acc0 = 0.f, acc1 = 0.f, acc2 = 0.f;
  const int* ad = (const int*)&av;
  const int* bd = (const int*)&bv;
#pragma unroll
  for (int d = 0; d < 4; ++d) {
    int A = ad[d], B = bd[d];
    float a0 = __int_as_float(A << 16);
    float a1 = __int_as_float(A & 0xffff0000);
    float b0 = __int_as_float(B << 16);
    float b1 = __int_as_float(B & 0xffff0000);
    float e0 = fmaxf(a0 + b0, 0.f);
    float e1 = fmaxf(a1 + b1, 0.f);
    int h = sub * 8 + d * 2;
    acc0 = fmaf(e0, ew2[h * 3 + 0], acc0);
    acc1 = fmaf(e0, ew2[h * 3 + 1], acc1);
    acc2 = fmaf(e0, ew2[h * 3 + 2], acc2);
    acc0 = fmaf(e1, ew2[h * 3 + 3], acc0);
    acc1 = fmaf(e1, ew2[h * 3 + 4], acc1);
    acc2 = fmaf(e1, ew2[h * 3 + 5], acc2);
  }
  acc0 += __shfl_xor(acc0, 1, 64); acc0 += __shfl_xor(acc0, 2, 64); acc0 += __shfl_xor(acc0, 4, 64);
  acc1 += __shfl_xor(acc1, 1, 64); acc1 += __shfl_xor(acc1, 2, 64); acc1 += __shfl_xor(acc1, 4, 64);
  acc2 += __shfl_xor(acc2, 1, 64); acc2 += __shfl_xor(acc2, 2, 64); acc2 += __shfl_xor(acc2, 4, 64);
  if (sub == 0) {
    float l0 = acc0 + eb2[0], l1 = acc1 + eb2[1], l2 = acc2 + eb2[2];
    float mx = fmaxf(l0, fmaxf(l1, l2));
    float ls = mx + logf(expf(l0 - mx) + expf(l1 - mx) + expf(l2 - mx));
    out[e * 3 + 0] = l0 - ls;
    out[e * 3 + 1] = l1 - ls;
    out[e * 3 + 2] = l2 - ls;
  }
}

// ---------------------------------------------------------------------------
// Node head: one thread per node (x3 fp32).
// ---------------------------------------------------------------------------
__global__ __launch_bounds__(256) void node_head_kernel(const float* __restrict__ x3,
                                                        const float* __restrict__ nw1,
                                                        const float* __restrict__ nb1,
                                                        const float* __restrict__ nw2,
                                                        const float* __restrict__ nb2,
                                                        float* __restrict__ out) {
  __shared__ float w1s[64 * 32];
  __shared__ float w2s[64];
  for (int i = threadIdx.x; i < 2048; i += 256) w1s[i] = nw1[i];
  if (threadIdx.x < 64) w2s[threadIdx.x] = nw2[threadIdx.x];
  __syncthreads();
  int n = blockIdx.x * 256 + threadIdx.x;
  if (n >= Nn) return;
  float acc[32];
#pragma unroll
  for (int c = 0; c < 32; ++c) acc[c] = nb1[c];
  for (int k = 0; k < 64; ++k) {
    float xv = x3[(long)n * 64 + k];
#pragma unroll
    for (int c = 0; c < 32; ++c) acc[c] += xv * w1s[k * 32 + c];
  }
  float l0 = nb2[0], l1 = nb2[1];
#pragma unroll
  for (int c = 0; c < 32; ++c) {
    float h = fmaxf(acc[c], 0.f);
    l0 += h * w2s[c * 2 + 0];
    l1 += h * w2s[c * 2 + 1];
  }
  float mx = fmaxf(l0, l1);
  float ls = mx + logf(expf(l0 - mx) + expf(l1 - mx));
  out[(long)3 * Ee + (long)n * 2 + 0] = l0 - ls;
  out[(long)3 * Ee + (long)n * 2 + 1] = l1 - ls;
}

// ---------------------------------------------------------------------------
extern "C" void kernel_launch(void* const* d_in, const int* in_sizes, int n_in,
                              void* d_out, int out_size, void* d_ws, size_t ws_size,
                              hipStream_t stream) {
  const float* x = (const float*)d_in[0];
  const int* ei = (const int*)d_in[1];
  const int* et = (const int*)d_in[2];
  const float* W1 = (const float*)d_in[3];
  const float* root1 = (const float*)d_in[4];
  const float* b1 = (const float*)d_in[5];
  const float* W2 = (const float*)d_in[6];
  const float* root2 = (const float*)d_in[7];
  const float* b2 = (const float*)d_in[8];
  const float* W3 = (const float*)d_in[9];
  const float* root3 = (const float*)d_in[10];
  const float* b3 = (const float*)d_in[11];
  const float* lng = (const float*)d_in[12];
  const float* lnb = (const float*)d_in[13];
  const float* ew1 = (const float*)d_in[14];
  const float* eb1 = (const float*)d_in[15];
  const float* ew2 = (const float*)d_in[16];
  const float* eb2 = (const float*)d_in[17];
  const float* nw1 = (const float*)d_in[18];
  const float* nb1 = (const float*)d_in[19];
  const float* nw2 = (const float*)d_in[20];
  const float* nb2 = (const float*)d_in[21];
  float* out = (float*)d_out;

  char* p = (char*)d_ws;
  size_t off = 0;
  auto alloc = [&](size_t bytes) {
    void* r = p + off;
    off += (bytes + 255) & ~(size_t)255;
    return r;
  };
  // Workspace kept within the proven footprint: rank/counts ALIAS xA/xB
  // (rank & counts are dead before xA/xB's first writes in layer-1/2 agg).
  unsigned short* XR = (unsigned short*)alloc((size_t)Nn * 256 * 2);  // bf16; also AB
  float* xA = (float*)alloc((size_t)Nn * 64 * 4);
  float* xB = (float*)alloc((size_t)Nn * 64 * 4);
  int* srcs = (int*)alloc((size_t)Ee * 4);
  int* offs = (int*)alloc((size_t)(RN + 1) * 4);
  int* bsums = (int*)alloc(1024);
  unsigned short* Wt1 = (unsigned short*)alloc((size_t)256 * KPAD1 * 2);
  unsigned short* Wt2 = (unsigned short*)alloc((size_t)256 * 64 * 2);
  unsigned short* Wt3 = (unsigned short*)alloc((size_t)256 * 64 * 2);
  unsigned short* Wth = (unsigned short*)alloc((size_t)256 * 64 * 2);
  float* biasH = (float*)alloc(128 * 4);
  int* rank = (int*)xA;     // Ee*4 = 6.4MB <= 12.8MB; dead before xA written
  int* counts = (int*)xB;   // RN*4 = 0.6MB <= 12.8MB; dead before xB written

  int nb = (RN + 1023) / 1024;  // 147

  // --- CSR build (rank captured in count pass; fill is atomic-free) ---
  hipMemsetAsync(counts, 0, (size_t)RN * 4, stream);
  count_kernel<<<(Ee + 255) / 256, 256, 0, stream>>>(ei, et, counts, rank);
  scan1_kernel<<<nb, 256, 0, stream>>>(counts, offs, bsums, RN);
  scan_top_kernel<<<1, 256, 0, stream>>>(bsums, nb);
  scan_add_kernel<<<(RN + 256) / 256 + 1, 256, 0, stream>>>(offs, bsums, RN);
  fill_kernel<<<(Ee + 255) / 256, 256, 0, stream>>>(ei, et, offs, rank, srcs);

  // --- weight prep (bf16 transposed) ---
  prep_wt_kernel<<<(256 * KPAD1 + 255) / 256, 256, 0, stream>>>(W1, root1, Wt1, FIN, KPAD1);
  prep_wt_kernel<<<(256 * 64 + 255) / 256, 256, 0, stream>>>(W2, root2, Wt2, 64, 64);
  prep_wt_kernel<<<(256 * 64 + 255) / 256, 256, 0, stream>>>(W3, root3, Wt3, 64, 64);
  prep_wth_kernel<<<(256 * 64 + 255) / 256, 256, 0, stream>>>(ew1, eb1, Wth, biasH);

  int gemmBlocks = (Nn + 255) / 256;  // 196
  int aggBlocks = (Nn + 3) / 4;

  // --- layer 1 ---
  gemm_bf16_kernel<<<gemmBlocks, 1024, 0, stream>>>(x, Wt1, XR, nullptr, Nn, FIN, KPAD1, 256);
  agg_kernel<<<aggBlocks, 256, 0, stream>>>(XR, offs, srcs, b1, nullptr, nullptr, xA, 0);
  // --- layer 2 ---
  gemm_bf16_kernel<<<gemmBlocks, 1024, 0, stream>>>(xA, Wt2, XR, nullptr, Nn, 64, 64, 256);
  agg_kernel<<<aggBlocks, 256, 0, stream>>>(XR, offs, srcs, b2, nullptr, nullptr, xB, 0);
  // --- layer 3 + layernorm ---
  gemm_bf16_kernel<<<gemmBlocks, 1024, 0, stream>>>(xB, Wt3, XR, nullptr, Nn, 64, 64, 256);
  agg_kernel<<<aggBlocks, 256, 0, stream>>>(XR, offs, srcs, b3, lng, lnb, xA, 1);

  // --- heads ---
  gemm_bf16_kernel<<<gemmBlocks, 1024, 0, stream>>>(xA, Wth, XR, biasH, Nn, 64, 64, 128);
  edge_head_kernel<<<(Ee + 31) / 32, 256, 0, stream>>>(XR, ei, ew2, eb2, out);
  node_head_kernel<<<(Nn + 255) / 256, 256, 0, stream>>>(xA, nw1, nb1, nw2, nb2, out);
}

// Round 14
// 665.194 us; speedup vs baseline: 1.1140x; 1.0208x over previous
//
#include <hip/hip_runtime.h>
#include <hip/hip_bf16.h>
#include <math.h>

#define Nn 50000
#define Ee 1600000
#define RR 3
#define RN (RR * Nn)
#define FIN 770
#define KPAD1 800

typedef __attribute__((ext_vector_type(8))) short short8;
typedef __attribute__((ext_vector_type(4))) float floatx4;

static __device__ __forceinline__ unsigned short f2bf(float v) {
  __hip_bfloat16 h = __float2bfloat16(v);
  return *(unsigned short*)&h;
}

// ---------------------------------------------------------------------------
// CSR build: count (atomic, returns rank) -> exclusive scan -> atomic-free fill
// ---------------------------------------------------------------------------
__global__ __launch_bounds__(256) void count_kernel(const int* __restrict__ ei,
                                                    const int* __restrict__ et,
                                                    int* __restrict__ counts,
                                                    int* __restrict__ rank) {
  int e = blockIdx.x * 256 + threadIdx.x;
  if (e >= Ee) return;
  int col = ei[Ee + e];
  int r = et[e];
  rank[e] = atomicAdd(&counts[r * Nn + col], 1);
}

__global__ __launch_bounds__(256) void scan1_kernel(const int* __restrict__ counts,
                                                    int* __restrict__ offs,
                                                    int* __restrict__ bsums, int n) {
  __shared__ int sh[256];
  int t = threadIdx.x;
  int base = blockIdx.x * 1024 + t * 4;
  int v0 = (base + 0 < n) ? counts[base + 0] : 0;
  int v1 = (base + 1 < n) ? counts[base + 1] : 0;
  int v2 = (base + 2 < n) ? counts[base + 2] : 0;
  int v3 = (base + 3 < n) ? counts[base + 3] : 0;
  int tot = v0 + v1 + v2 + v3;
  sh[t] = tot;
  __syncthreads();
  for (int off = 1; off < 256; off <<= 1) {
    int v = (t >= off) ? sh[t - off] : 0;
    __syncthreads();
    sh[t] += v;
    __syncthreads();
  }
  int run = sh[t] - tot;
  if (base + 0 < n) offs[base + 0] = run; run += v0;
  if (base + 1 < n) offs[base + 1] = run; run += v1;
  if (base + 2 < n) offs[base + 2] = run; run += v2;
  if (base + 3 < n) offs[base + 3] = run;
  if (t == 255) bsums[blockIdx.x] = sh[255];
}

__global__ __launch_bounds__(256) void scan_top_kernel(int* __restrict__ bsums, int nb) {
  __shared__ int sh[256];
  int t = threadIdx.x;
  int v = (t < nb) ? bsums[t] : 0;
  sh[t] = v;
  __syncthreads();
  for (int off = 1; off < 256; off <<= 1) {
    int x = (t >= off) ? sh[t - off] : 0;
    __syncthreads();
    sh[t] += x;
    __syncthreads();
  }
  if (t < nb) bsums[t] = sh[t] - v;
}

__global__ __launch_bounds__(256) void scan_add_kernel(int* __restrict__ offs,
                                                       const int* __restrict__ bsums,
                                                       int n) {
  int i = blockIdx.x * 256 + threadIdx.x;
  if (i > n) return;
  if (i == n) { offs[n] = Ee; return; }
  offs[i] += bsums[i >> 10];
}

__global__ __launch_bounds__(256) void fill_kernel(const int* __restrict__ ei,
                                                   const int* __restrict__ et,
                                                   const int* __restrict__ offs,
                                                   const int* __restrict__ rank,
                                                   int* __restrict__ srcs) {
  int e = blockIdx.x * 256 + threadIdx.x;
  if (e >= Ee) return;
  int row = ei[e];
  int col = ei[Ee + e];
  int r = et[e];
  int s = r * Nn + col;
  srcs[offs[s] + rank[e]] = row;   // atomic-free: rank captured in count pass
}

// ---------------------------------------------------------------------------
// Weight prep: Wt (bf16, n-major) [256][Kpad]; cols 0..191 = W[r], 192..255 = root
// ---------------------------------------------------------------------------
__global__ __launch_bounds__(256) void prep_wt_kernel(const float* __restrict__ W,
                                                      const float* __restrict__ root,
                                                      unsigned short* __restrict__ Wt,
                                                      int K, int Kpad) {
  int i = blockIdx.x * 256 + threadIdx.x;
  if (i >= 256 * Kpad) return;
  int c = i / Kpad, k = i % Kpad;
  float v = 0.f;
  if (k < K) {
    if (c < 192) {
      int r = c >> 6, h = c & 63;
      v = W[((long)r * K + k) * 64 + h];
    } else {
      v = root[k * 64 + (c - 192)];
    }
  }
  Wt[i] = f2bf(v);
}

// head weights: Wt_h [256][64] bf16 (rows 128..255 zero), biasH[128] fp32
__global__ __launch_bounds__(256) void prep_wth_kernel(const float* __restrict__ ew1,
                                                       const float* __restrict__ eb1,
                                                       unsigned short* __restrict__ Wth,
                                                       float* __restrict__ biasH) {
  int i = blockIdx.x * 256 + threadIdx.x;
  if (i < 128) biasH[i] = (i < 64) ? eb1[i] : 0.f;
  if (i >= 256 * 64) return;
  int c = i >> 6, k = i & 63;
  float v = 0.f;
  if (c < 64) v = ew1[k * 64 + c];
  else if (c < 128) v = ew1[(64 + k) * 64 + (c - 64)];
  Wth[i] = f2bf(v);
}

// ---------------------------------------------------------------------------
// bf16 MFMA GEMM v9: R9/R11-proven schedule (256x256, BK=32, 1024 thr, 16
// waves, grid 196 = 1 round — verified local optimum, do not touch), plus a
// bf16-A fast path (aBf16=1): A rows already bf16 -> 1 int4 load, direct LDS
// store, zero cvt. Numerics identical (fp32 path converted to bf16 anyway).
// ---------------------------------------------------------------------------
#define ASTR 40
#define BSTR 40

#define LOAD_A_FULL(k0)                                        \
  {                                                            \
    const float* ap = aRow + (k0) + ac;                        \
    a01 = *(const float4*)(ap + 0);                            \
    a23 = *(const float4*)(ap + 4);                            \
  }
#define LOAD_A_MASK(k0)                                        \
  {                                                            \
    int kb = (k0) + ac;                                        \
    a01.x = (rowOK && kb + 0 < K) ? aRow[kb + 0] : 0.f;        \
    a01.y = (rowOK && kb + 1 < K) ? aRow[kb + 1] : 0.f;        \
    a01.z = (rowOK && kb + 2 < K) ? aRow[kb + 2] : 0.f;        \
    a01.w = (rowOK && kb + 3 < K) ? aRow[kb + 3] : 0.f;        \
    a23.x = (rowOK && kb + 4 < K) ? aRow[kb + 4] : 0.f;        \
    a23.y = (rowOK && kb + 5 < K) ? aRow[kb + 5] : 0.f;        \
    a23.z = (rowOK && kb + 6 < K) ? aRow[kb + 6] : 0.f;        \
    a23.w = (rowOK && kb + 7 < K) ? aRow[kb + 7] : 0.f;        \
  }
#define LOAD_A(k0)                                                   \
  {                                                                  \
    if (aBf16) { aB = *(const int4*)(aRowB + (k0) + ac); }           \
    else if (rowOK && (k0) + 32 <= K) LOAD_A_FULL(k0)                \
    else LOAD_A_MASK(k0)                                             \
  }
#define LOAD_B(k0)                                             \
  {                                                            \
    b0 = *(const int4*)(wRow + (k0));                          \
  }
#define STORE_TILE()                                                          \
  {                                                                           \
    if (aBf16) {                                                              \
      *(int4*)&As[ar * ASTR + ac] = aB;                                       \
    } else {                                                                  \
      __hip_bfloat162* adst = (__hip_bfloat162*)&As[ar * ASTR + ac];          \
      adst[0] = __hip_bfloat162(__float2bfloat16(a01.x), __float2bfloat16(a01.y)); \
      adst[1] = __hip_bfloat162(__float2bfloat16(a01.z), __float2bfloat16(a01.w)); \
      adst[2] = __hip_bfloat162(__float2bfloat16(a23.x), __float2bfloat16(a23.y)); \
      adst[3] = __hip_bfloat162(__float2bfloat16(a23.z), __float2bfloat16(a23.w)); \
    }                                                                         \
    *(int4*)&Bs[br * BSTR + bo] = b0;                                         \
  }

__global__ __launch_bounds__(1024) void gemm_bf16_kernel(
    const void* __restrict__ Ag, const unsigned short* __restrict__ Wt,
    unsigned short* __restrict__ Cg, const float* __restrict__ bias,
    int M, int K, int Kpad, int Ncol, int aBf16) {
  __shared__ unsigned short As[256 * ASTR];
  __shared__ unsigned short Bs[256 * BSTR];
  int t = threadIdx.x;
  int lane = t & 63;
  int wid = t >> 6;              // 0..15
  int quad = lane >> 4;
  int l16 = lane & 15;
  int rowBase = blockIdx.x * 256;
  int mbase = (wid >> 2) * 64;   // 0,64,128,192
  int nbase = (wid & 3) * 64;    // 0,64,128,192

  floatx4 acc[4][4];
#pragma unroll
  for (int i = 0; i < 4; ++i)
#pragma unroll
    for (int j = 0; j < 4; ++j) acc[i][j] = (floatx4){0.f, 0.f, 0.f, 0.f};

  int ar = t >> 2;               // 0..255 : A row
  int ac = (t & 3) * 8;          // 0..24  : 8 elements per thread
  long gm = rowBase + ar;
  bool rowOK = (gm < M);
  const float* aRow = (const float*)Ag + gm * (long)K;
  const unsigned short* aRowB = (const unsigned short*)Ag + gm * (long)K;
  int br = t >> 2;               // 0..255 : B row
  int bo = (t & 3) * 8;          // 0..24  : 8 bf16 per thread
  const unsigned short* wRow = Wt + (size_t)br * Kpad + bo;

  float4 a01, a23;   // prefetched A fp32 (8 fp32)
  int4 aB;           // prefetched A bf16 (8 bf16)
  int4 b0;           // prefetched B (8 bf16)

  int KT = Kpad / 32;
  LOAD_A(0);
  LOAD_B(0);

  for (int kt = 0; kt < KT; ++kt) {
    STORE_TILE();
    __syncthreads();

    // issue next tile's global loads FIRST (overlap with ds_read + MFMA)
    if (kt + 1 < KT) {
      int k0n = (kt + 1) * 32;
      LOAD_A(k0n);
      LOAD_B(k0n);
    }

    short8 af[4], bfr[4];
#pragma unroll
    for (int i = 0; i < 4; ++i)
      af[i] = *(const short8*)&As[(mbase + i * 16 + l16) * ASTR + quad * 8];
#pragma unroll
    for (int j = 0; j < 4; ++j)
      bfr[j] = *(const short8*)&Bs[(nbase + j * 16 + l16) * BSTR + quad * 8];

#pragma unroll
    for (int i = 0; i < 4; ++i)
#pragma unroll
      for (int j = 0; j < 4; ++j)
        acc[i][j] = __builtin_amdgcn_mfma_f32_16x16x32_bf16(af[i], bfr[j], acc[i][j], 0, 0, 0);
    __syncthreads();
  }

#pragma unroll
  for (int j = 0; j < 4; ++j) {
    int gn = nbase + j * 16 + l16;
    if (gn >= Ncol) continue;
    float bv = bias ? bias[gn] : 0.f;
#pragma unroll
    for (int i = 0; i < 4; ++i) {
      int gm0 = rowBase + mbase + i * 16 + quad * 4;
#pragma unroll
      for (int r = 0; r < 4; ++r) {
        int gmm = gm0 + r;
        if (gmm < M) Cg[(long)gmm * Ncol + gn] = f2bf(acc[i][j][r] + bv);
      }
    }
  }
}

// ---------------------------------------------------------------------------
// Aggregation v5 (bf16 XR): flattened 3-relation loop + 2-DEEP GATHER UNROLL
// (edges i and i+8 in flight together; tail edge masked via inv=0 with a
// valid address). Mode 0 writes bf16 (consumed by bf16-A gemm, numerics
// identical to prior fp32-write + gemm-side cvt). Mode 1 writes fp32.
// ---------------------------------------------------------------------------
#define AGG_RESOLVE(ii, ee, vv, rr)                                   \
  {                                                                   \
    if ((ii) < c0)       { ee = b0 + (ii);         vv = inv0; rr = 0; }   \
    else if ((ii) < c01) { ee = b1 + ((ii) - c0);  vv = inv1; rr = 64; }  \
    else                 { ee = b2 + ((ii) - c01); vv = inv2; rr = 128; } \
  }
#define AGG_FMA8(v, inv)                                              \
  {                                                                   \
    unsigned u0 = (unsigned)v.x, u1 = (unsigned)v.y;                  \
    unsigned u2 = (unsigned)v.z, u3 = (unsigned)v.w;                  \
    a0 = fmaf(__int_as_float(u0 << 16), inv, a0);                     \
    a1 = fmaf(__int_as_float(u0 & 0xffff0000u), inv, a1);             \
    a2 = fmaf(__int_as_float(u1 << 16), inv, a2);                     \
    a3 = fmaf(__int_as_float(u1 & 0xffff0000u), inv, a3);             \
    a4 = fmaf(__int_as_float(u2 << 16), inv, a4);                     \
    a5 = fmaf(__int_as_float(u2 & 0xffff0000u), inv, a5);             \
    a6 = fmaf(__int_as_float(u3 << 16), inv, a6);                     \
    a7 = fmaf(__int_as_float(u3 & 0xffff0000u), inv, a7);             \
  }

__global__ __launch_bounds__(256) void agg_kernel(const unsigned short* __restrict__ XR,
                                                  const int* __restrict__ offs,
                                                  const int* __restrict__ srcs,
                                                  const float* __restrict__ bias,
                                                  const float* __restrict__ lng,
                                                  const float* __restrict__ lnb,
                                                  float* __restrict__ out, int mode) {
  int lane = threadIdx.x & 63;
  int wid = threadIdx.x >> 6;
  int slot = lane >> 3;     // 0..7 : edge slot
  int l8 = lane & 7;        // h-chunk: h = l8*8 .. l8*8+7
  int dst = blockIdx.x * 4 + wid;
  if (dst >= Nn) return;

  int b0 = offs[dst],          e0 = offs[dst + 1];
  int b1 = offs[Nn + dst],     e1 = offs[Nn + dst + 1];
  int b2 = offs[2 * Nn + dst], e2 = offs[2 * Nn + dst + 1];
  int c0 = e0 - b0, c1 = e1 - b1, c2 = e2 - b2;
  int c01 = c0 + c1;
  int tot = c01 + c2;
  float inv0 = (c0 > 0) ? 1.f / (float)c0 : 0.f;
  float inv1 = (c1 > 0) ? 1.f / (float)c1 : 0.f;
  float inv2 = (c2 > 0) ? 1.f / (float)c2 : 0.f;

  float a0 = 0.f, a1 = 0.f, a2 = 0.f, a3 = 0.f;
  float a4 = 0.f, a5 = 0.f, a6 = 0.f, a7 = 0.f;
  for (int i = slot; i < tot; i += 16) {
    int ea; float iva; int ra;
    AGG_RESOLVE(i, ea, iva, ra);
    int ib = i + 8;
    int eb; float ivb; int rb;
    if (ib < tot) { AGG_RESOLVE(ib, eb, ivb, rb); }
    else          { eb = ea; ivb = 0.f; rb = ra; }
    int sa = srcs[ea];
    int sb = srcs[eb];
    int4 va = *(const int4*)&XR[(long)sa * 256 + ra + l8 * 8];
    int4 vb = *(const int4*)&XR[(long)sb * 256 + rb + l8 * 8];
    AGG_FMA8(va, iva);
    AGG_FMA8(vb, ivb);
  }
  // cross-slot reduction (lanes differing in bits 3..5)
#pragma unroll
  for (int m = 8; m < 64; m <<= 1) {
    a0 += __shfl_xor(a0, m, 64); a1 += __shfl_xor(a1, m, 64);
    a2 += __shfl_xor(a2, m, 64); a3 += __shfl_xor(a3, m, 64);
    a4 += __shfl_xor(a4, m, 64); a5 += __shfl_xor(a5, m, 64);
    a6 += __shfl_xor(a6, m, 64); a7 += __shfl_xor(a7, m, 64);
  }

  int4 rt = *(const int4*)&XR[(long)dst * 256 + 192 + l8 * 8];
  unsigned r0 = (unsigned)rt.x, r1 = (unsigned)rt.y;
  unsigned r2 = (unsigned)rt.z, r3 = (unsigned)rt.w;
  float4 bv0 = *(const float4*)&bias[l8 * 8];
  float4 bv1 = *(const float4*)&bias[l8 * 8 + 4];
  float t0 = a0 + __int_as_float(r0 << 16) + bv0.x;
  float t1 = a1 + __int_as_float(r0 & 0xffff0000u) + bv0.y;
  float t2 = a2 + __int_as_float(r1 << 16) + bv0.z;
  float t3 = a3 + __int_as_float(r1 & 0xffff0000u) + bv0.w;
  float t4 = a4 + __int_as_float(r2 << 16) + bv1.x;
  float t5 = a5 + __int_as_float(r2 & 0xffff0000u) + bv1.y;
  float t6 = a6 + __int_as_float(r3 << 16) + bv1.z;
  float t7 = a7 + __int_as_float(r3 & 0xffff0000u) + bv1.w;

  if (mode == 0) {
    if (slot == 0) {
      unsigned short* outB = (unsigned short*)out;
      int4 o;
      o.x = (int)((unsigned)f2bf(fmaxf(t0, 0.f)) | ((unsigned)f2bf(fmaxf(t1, 0.f)) << 16));
      o.y = (int)((unsigned)f2bf(fmaxf(t2, 0.f)) | ((unsigned)f2bf(fmaxf(t3, 0.f)) << 16));
      o.z = (int)((unsigned)f2bf(fmaxf(t4, 0.f)) | ((unsigned)f2bf(fmaxf(t5, 0.f)) << 16));
      o.w = (int)((unsigned)f2bf(fmaxf(t6, 0.f)) | ((unsigned)f2bf(fmaxf(t7, 0.f)) << 16));
      *(int4*)&outB[(long)dst * 64 + l8 * 8] = o;
    }
  } else {
    float s = t0 + t1 + t2 + t3 + t4 + t5 + t6 + t7;
    s += __shfl_xor(s, 1, 64); s += __shfl_xor(s, 2, 64); s += __shfl_xor(s, 4, 64);
    float mu = s * (1.f / 64.f);
    float d0 = t0 - mu, d1 = t1 - mu, d2 = t2 - mu, d3 = t3 - mu;
    float d4 = t4 - mu, d5 = t5 - mu, d6 = t6 - mu, d7 = t7 - mu;
    float vv = d0 * d0 + d1 * d1 + d2 * d2 + d3 * d3 +
               d4 * d4 + d5 * d5 + d6 * d6 + d7 * d7;
    vv += __shfl_xor(vv, 1, 64); vv += __shfl_xor(vv, 2, 64); vv += __shfl_xor(vv, 4, 64);
    float rstd = rsqrtf(vv * (1.f / 64.f) + 1e-5f);
    if (slot == 0) {
      float4 g0 = *(const float4*)&lng[l8 * 8];
      float4 g1 = *(const float4*)&lng[l8 * 8 + 4];
      float4 c0v = *(const float4*)&lnb[l8 * 8];
      float4 c1v = *(const float4*)&lnb[l8 * 8 + 4];
      float4 o0, o1;
      o0.x = d0 * rstd * g0.x + c0v.x;
      o0.y = d1 * rstd * g0.y + c0v.y;
      o0.z = d2 * rstd * g0.z + c0v.z;
      o0.w = d3 * rstd * g0.w + c0v.w;
      o1.x = d4 * rstd * g1.x + c1v.x;
      o1.y = d5 * rstd * g1.y + c1v.y;
      o1.z = d6 * rstd * g1.z + c1v.z;
      o1.w = d7 * rstd * g1.w + c1v.w;
      *(float4*)&out[(long)dst * 64 + l8 * 8] = o0;
      *(float4*)&out[(long)dst * 64 + l8 * 8 + 4] = o1;
    }
  }
}

// ---------------------------------------------------------------------------
// Edge head v3: 8 lanes per edge, each lane exactly ONE int4 per endpoint
// (8 h values, 24 FMAs); 3-level shfl; sublane 0 does log-softmax + write.
// ---------------------------------------------------------------------------
__global__ __launch_bounds__(256) void edge_head_kernel(const unsigned short* __restrict__ AB,
                                                        const int* __restrict__ ei,
                                                        const float* __restrict__ ew2,
                                                        const float* __restrict__ eb2,
                                                        float* __restrict__ out) {
  int t = threadIdx.x;
  long e = (long)blockIdx.x * 32 + (t >> 3);
  if (e >= Ee) return;
  int sub = t & 7;
  int row = ei[e];
  int col = ei[Ee + e];
  int4 av = *(const int4*)&AB[(long)row * 128 + sub * 8];
  int4 bv = *(const int4*)&AB[(long)col * 128 + 64 + sub * 8];
  float acc0 = 0.f, acc1 = 0.f, acc2 = 0.f;
  const int* ad = (const int*)&av;
  const int* bd = (const int*)&bv;
#pragma unroll
  for (int d = 0; d < 4; ++d) {
    int A = ad[d], B = bd[d];
    float a0 = __int_as_float(A << 16);
    float a1 = __int_as_float(A & 0xffff0000);
    float b0 = __int_as_float(B << 16);
    float b1 = __int_as_float(B & 0xffff0000);
    float e0 = fmaxf(a0 + b0, 0.f);
    float e1 = fmaxf(a1 + b1, 0.f);
    int h = sub * 8 + d * 2;
    acc0 = fmaf(e0, ew2[h * 3 + 0], acc0);
    acc1 = fmaf(e0, ew2[h * 3 + 1], acc1);
    acc2 = fmaf(e0, ew2[h * 3 + 2], acc2);
    acc0 = fmaf(e1, ew2[h * 3 + 3], acc0);
    acc1 = fmaf(e1, ew2[h * 3 + 4], acc1);
    acc2 = fmaf(e1, ew2[h * 3 + 5], acc2);
  }
  acc0 += __shfl_xor(acc0, 1, 64); acc0 += __shfl_xor(acc0, 2, 64); acc0 += __shfl_xor(acc0, 4, 64);
  acc1 += __shfl_xor(acc1, 1, 64); acc1 += __shfl_xor(acc1, 2, 64); acc1 += __shfl_xor(acc1, 4, 64);
  acc2 += __shfl_xor(acc2, 1, 64); acc2 += __shfl_xor(acc2, 2, 64); acc2 += __shfl_xor(acc2, 4, 64);
  if (sub == 0) {
    float l0 = acc0 + eb2[0], l1 = acc1 + eb2[1], l2 = acc2 + eb2[2];
    float mx = fmaxf(l0, fmaxf(l1, l2));
    float ls = mx + logf(expf(l0 - mx) + expf(l1 - mx) + expf(l2 - mx));
    out[e * 3 + 0] = l0 - ls;
    out[e * 3 + 1] = l1 - ls;
    out[e * 3 + 2] = l2 - ls;
  }
}

// ---------------------------------------------------------------------------
// Node head: one thread per node (x3 fp32).
// ---------------------------------------------------------------------------
__global__ __launch_bounds__(256) void node_head_kernel(const float* __restrict__ x3,
                                                        const float* __restrict__ nw1,
                                                        const float* __restrict__ nb1,
                                                        const float* __restrict__ nw2,
                                                        const float* __restrict__ nb2,
                                                        float* __restrict__ out) {
  __shared__ float w1s[64 * 32];
  __shared__ float w2s[64];
  for (int i = threadIdx.x; i < 2048; i += 256) w1s[i] = nw1[i];
  if (threadIdx.x < 64) w2s[threadIdx.x] = nw2[threadIdx.x];
  __syncthreads();
  int n = blockIdx.x * 256 + threadIdx.x;
  if (n >= Nn) return;
  float acc[32];
#pragma unroll
  for (int c = 0; c < 32; ++c) acc[c] = nb1[c];
  for (int k = 0; k < 64; ++k) {
    float xv = x3[(long)n * 64 + k];
#pragma unroll
    for (int c = 0; c < 32; ++c) acc[c] += xv * w1s[k * 32 + c];
  }
  float l0 = nb2[0], l1 = nb2[1];
#pragma unroll
  for (int c = 0; c < 32; ++c) {
    float h = fmaxf(acc[c], 0.f);
    l0 += h * w2s[c * 2 + 0];
    l1 += h * w2s[c * 2 + 1];
  }
  float mx = fmaxf(l0, l1);
  float ls = mx + logf(expf(l0 - mx) + expf(l1 - mx));
  out[(long)3 * Ee + (long)n * 2 + 0] = l0 - ls;
  out[(long)3 * Ee + (long)n * 2 + 1] = l1 - ls;
}

// ---------------------------------------------------------------------------
extern "C" void kernel_launch(void* const* d_in, const int* in_sizes, int n_in,
                              void* d_out, int out_size, void* d_ws, size_t ws_size,
                              hipStream_t stream) {
  const float* x = (const float*)d_in[0];
  const int* ei = (const int*)d_in[1];
  const int* et = (const int*)d_in[2];
  const float* W1 = (const float*)d_in[3];
  const float* root1 = (const float*)d_in[4];
  const float* b1 = (const float*)d_in[5];
  const float* W2 = (const float*)d_in[6];
  const float* root2 = (const float*)d_in[7];
  const float* b2 = (const float*)d_in[8];
  const float* W3 = (const float*)d_in[9];
  const float* root3 = (const float*)d_in[10];
  const float* b3 = (const float*)d_in[11];
  const float* lng = (const float*)d_in[12];
  const float* lnb = (const float*)d_in[13];
  const float* ew1 = (const float*)d_in[14];
  const float* eb1 = (const float*)d_in[15];
  const float* ew2 = (const float*)d_in[16];
  const float* eb2 = (const float*)d_in[17];
  const float* nw1 = (const float*)d_in[18];
  const float* nb1 = (const float*)d_in[19];
  const float* nw2 = (const float*)d_in[20];
  const float* nb2 = (const float*)d_in[21];
  float* out = (float*)d_out;

  char* p = (char*)d_ws;
  size_t off = 0;
  auto alloc = [&](size_t bytes) {
    void* r = p + off;
    off += (bytes + 255) & ~(size_t)255;
    return r;
  };
  // Workspace kept within the proven footprint: rank/counts ALIAS xA/xB
  // (rank & counts are dead before xA/xB's first writes in layer-1/2 agg).
  unsigned short* XR = (unsigned short*)alloc((size_t)Nn * 256 * 2);  // bf16; also AB
  float* xA = (float*)alloc((size_t)Nn * 64 * 4);   // fp32 (mode1) or bf16 (mode0)
  float* xB = (float*)alloc((size_t)Nn * 64 * 4);
  int* srcs = (int*)alloc((size_t)Ee * 4);
  int* offs = (int*)alloc((size_t)(RN + 1) * 4);
  int* bsums = (int*)alloc(1024);
  unsigned short* Wt1 = (unsigned short*)alloc((size_t)256 * KPAD1 * 2);
  unsigned short* Wt2 = (unsigned short*)alloc((size_t)256 * 64 * 2);
  unsigned short* Wt3 = (unsigned short*)alloc((size_t)256 * 64 * 2);
  unsigned short* Wth = (unsigned short*)alloc((size_t)256 * 64 * 2);
  float* biasH = (float*)alloc(128 * 4);
  int* rank = (int*)xA;     // Ee*4 = 6.4MB <= 12.8MB; dead before xA written
  int* counts = (int*)xB;   // RN*4 = 0.6MB <= 12.8MB; dead before xB written

  int nb = (RN + 1023) / 1024;  // 147

  // --- CSR build (rank captured in count pass; fill is atomic-free) ---
  hipMemsetAsync(counts, 0, (size_t)RN * 4, stream);
  count_kernel<<<(Ee + 255) / 256, 256, 0, stream>>>(ei, et, counts, rank);
  scan1_kernel<<<nb, 256, 0, stream>>>(counts, offs, bsums, RN);
  scan_top_kernel<<<1, 256, 0, stream>>>(bsums, nb);
  scan_add_kernel<<<(RN + 256) / 256 + 1, 256, 0, stream>>>(offs, bsums, RN);
  fill_kernel<<<(Ee + 255) / 256, 256, 0, stream>>>(ei, et, offs, rank, srcs);

  // --- weight prep (bf16 transposed) ---
  prep_wt_kernel<<<(256 * KPAD1 + 255) / 256, 256, 0, stream>>>(W1, root1, Wt1, FIN, KPAD1);
  prep_wt_kernel<<<(256 * 64 + 255) / 256, 256, 0, stream>>>(W2, root2, Wt2, 64, 64);
  prep_wt_kernel<<<(256 * 64 + 255) / 256, 256, 0, stream>>>(W3, root3, Wt3, 64, 64);
  prep_wth_kernel<<<(256 * 64 + 255) / 256, 256, 0, stream>>>(ew1, eb1, Wth, biasH);

  int gemmBlocks = (Nn + 255) / 256;  // 196
  int aggBlocks = (Nn + 3) / 4;

  // --- layer 1 ---
  gemm_bf16_kernel<<<gemmBlocks, 1024, 0, stream>>>(x, Wt1, XR, nullptr, Nn, FIN, KPAD1, 256, 0);
  agg_kernel<<<aggBlocks, 256, 0, stream>>>(XR, offs, srcs, b1, nullptr, nullptr, xA, 0);  // bf16 out
  // --- layer 2 ---
  gemm_bf16_kernel<<<gemmBlocks, 1024, 0, stream>>>(xA, Wt2, XR, nullptr, Nn, 64, 64, 256, 1);
  agg_kernel<<<aggBlocks, 256, 0, stream>>>(XR, offs, srcs, b2, nullptr, nullptr, xB, 0);  // bf16 out
  // --- layer 3 + layernorm ---
  gemm_bf16_kernel<<<gemmBlocks, 1024, 0, stream>>>(xB, Wt3, XR, nullptr, Nn, 64, 64, 256, 1);
  agg_kernel<<<aggBlocks, 256, 0, stream>>>(XR, offs, srcs, b3, lng, lnb, xA, 1);          // fp32 out
  // --- heads ---
  gemm_bf16_kernel<<<gemmBlocks, 1024, 0, stream>>>(xA, Wth, XR, biasH, Nn, 64, 64, 128, 0);
  edge_head_kernel<<<(Ee + 31) / 32, 256, 0, stream>>>(XR, ei, ew2, eb2, out);
  node_head_kernel<<<(Nn + 255) / 256, 256, 0, stream>>>(xA, nw1, nb1, nw2, nb2, out);
}

// Round 15
// 622.663 us; speedup vs baseline: 1.1901x; 1.0683x over previous
//
#include <hip/hip_runtime.h>
#include <hip/hip_bf16.h>
#include <math.h>

#define Nn 50000
#define Ee 1600000
#define RR 3
#define RN (RR * Nn)
#define FIN 770
#define KPAD1 800

typedef __attribute__((ext_vector_type(8))) short short8;
typedef __attribute__((ext_vector_type(4))) float floatx4;

static __device__ __forceinline__ unsigned short f2bf(float v) {
  __hip_bfloat16 h = __float2bfloat16(v);
  return *(unsigned short*)&h;
}

// ---------------------------------------------------------------------------
// CSR scan + fill (count is FUSED into gemm1's dispatch as tail blocks)
// ---------------------------------------------------------------------------
__global__ __launch_bounds__(256) void scan1_kernel(const int* __restrict__ counts,
                                                    int* __restrict__ offs,
                                                    int* __restrict__ bsums, int n) {
  __shared__ int sh[256];
  int t = threadIdx.x;
  int base = blockIdx.x * 1024 + t * 4;
  int v0 = (base + 0 < n) ? counts[base + 0] : 0;
  int v1 = (base + 1 < n) ? counts[base + 1] : 0;
  int v2 = (base + 2 < n) ? counts[base + 2] : 0;
  int v3 = (base + 3 < n) ? counts[base + 3] : 0;
  int tot = v0 + v1 + v2 + v3;
  sh[t] = tot;
  __syncthreads();
  for (int off = 1; off < 256; off <<= 1) {
    int v = (t >= off) ? sh[t - off] : 0;
    __syncthreads();
    sh[t] += v;
    __syncthreads();
  }
  int run = sh[t] - tot;
  if (base + 0 < n) offs[base + 0] = run; run += v0;
  if (base + 1 < n) offs[base + 1] = run; run += v1;
  if (base + 2 < n) offs[base + 2] = run; run += v2;
  if (base + 3 < n) offs[base + 3] = run;
  if (t == 255) bsums[blockIdx.x] = sh[255];
}

__global__ __launch_bounds__(256) void scan_top_kernel(int* __restrict__ bsums, int nb) {
  __shared__ int sh[256];
  int t = threadIdx.x;
  int v = (t < nb) ? bsums[t] : 0;
  sh[t] = v;
  __syncthreads();
  for (int off = 1; off < 256; off <<= 1) {
    int x = (t >= off) ? sh[t - off] : 0;
    __syncthreads();
    sh[t] += x;
    __syncthreads();
  }
  if (t < nb) bsums[t] = sh[t] - v;
}

__global__ __launch_bounds__(256) void scan_add_kernel(int* __restrict__ offs,
                                                       const int* __restrict__ bsums,
                                                       int n) {
  int i = blockIdx.x * 256 + threadIdx.x;
  if (i > n) return;
  if (i == n) { offs[n] = Ee; return; }
  offs[i] += bsums[i >> 10];
}

__global__ __launch_bounds__(256) void fill_kernel(const int* __restrict__ ei,
                                                   const int* __restrict__ et,
                                                   const int* __restrict__ offs,
                                                   const int* __restrict__ rank,
                                                   int* __restrict__ srcs) {
  int e = blockIdx.x * 256 + threadIdx.x;
  if (e >= Ee) return;
  int row = ei[e];
  int col = ei[Ee + e];
  int r = et[e];
  int s = r * Nn + col;
  srcs[offs[s] + rank[e]] = row;   // atomic-free: rank captured in count pass
}

// ---------------------------------------------------------------------------
// Weight prep: Wt (bf16, n-major) [256][Kpad]; cols 0..191 = W[r], 192..255 = root
// ---------------------------------------------------------------------------
__global__ __launch_bounds__(256) void prep_wt_kernel(const float* __restrict__ W,
                                                      const float* __restrict__ root,
                                                      unsigned short* __restrict__ Wt,
                                                      int K, int Kpad) {
  int i = blockIdx.x * 256 + threadIdx.x;
  if (i >= 256 * Kpad) return;
  int c = i / Kpad, k = i % Kpad;
  float v = 0.f;
  if (k < K) {
    if (c < 192) {
      int r = c >> 6, h = c & 63;
      v = W[((long)r * K + k) * 64 + h];
    } else {
      v = root[k * 64 + (c - 192)];
    }
  }
  Wt[i] = f2bf(v);
}

// head weights: Wt_h [256][64] bf16 (rows 128..255 zero), biasH[128] fp32
__global__ __launch_bounds__(256) void prep_wth_kernel(const float* __restrict__ ew1,
                                                       const float* __restrict__ eb1,
                                                       unsigned short* __restrict__ Wth,
                                                       float* __restrict__ biasH) {
  int i = blockIdx.x * 256 + threadIdx.x;
  if (i < 128) biasH[i] = (i < 64) ? eb1[i] : 0.f;
  if (i >= 256 * 64) return;
  int c = i >> 6, k = i & 63;
  float v = 0.f;
  if (c < 64) v = ew1[k * 64 + c];
  else if (c < 128) v = ew1[(64 + k) * 64 + (c - 64)];
  Wth[i] = f2bf(v);
}

// ---------------------------------------------------------------------------
// bf16 MFMA GEMM core: R9/R11-proven schedule (256x256, BK=32, 1024 thr, 16
// waves, grid 196 = 1 round — verified local optimum). bf16-A fast path
// (aBf16=1). Shared as a macro so fused kernels reuse it verbatim.
// ---------------------------------------------------------------------------
#define ASTR 40
#define BSTR 40

#define LOAD_A_FULL(k0)                                        \
  {                                                            \
    const float* ap = aRow + (k0) + ac;                        \
    a01 = *(const float4*)(ap + 0);                            \
    a23 = *(const float4*)(ap + 4);                            \
  }
#define LOAD_A_MASK(k0)                                        \
  {                                                            \
    int kb = (k0) + ac;                                        \
    a01.x = (rowOK && kb + 0 < K) ? aRow[kb + 0] : 0.f;        \
    a01.y = (rowOK && kb + 1 < K) ? aRow[kb + 1] : 0.f;        \
    a01.z = (rowOK && kb + 2 < K) ? aRow[kb + 2] : 0.f;        \
    a01.w = (rowOK && kb + 3 < K) ? aRow[kb + 3] : 0.f;        \
    a23.x = (rowOK && kb + 4 < K) ? aRow[kb + 4] : 0.f;        \
    a23.y = (rowOK && kb + 5 < K) ? aRow[kb + 5] : 0.f;        \
    a23.z = (rowOK && kb + 6 < K) ? aRow[kb + 6] : 0.f;        \
    a23.w = (rowOK && kb + 7 < K) ? aRow[kb + 7] : 0.f;        \
  }
#define LOAD_A(k0)                                                   \
  {                                                                  \
    if (aBf16) { aB = *(const int4*)(aRowB + (k0) + ac); }           \
    else if (rowOK && (k0) + 32 <= K) LOAD_A_FULL(k0)                \
    else LOAD_A_MASK(k0)                                             \
  }
#define LOAD_B(k0)                                             \
  {                                                            \
    b0 = *(const int4*)(wRow + (k0));                          \
  }
#define STORE_TILE()                                                          \
  {                                                                           \
    if (aBf16) {                                                              \
      *(int4*)&As[ar * ASTR + ac] = aB;                                       \
    } else {                                                                  \
      __hip_bfloat162* adst = (__hip_bfloat162*)&As[ar * ASTR + ac];          \
      adst[0] = __hip_bfloat162(__float2bfloat16(a01.x), __float2bfloat16(a01.y)); \
      adst[1] = __hip_bfloat162(__float2bfloat16(a01.z), __float2bfloat16(a01.w)); \
      adst[2] = __hip_bfloat162(__float2bfloat16(a23.x), __float2bfloat16(a23.y)); \
      adst[3] = __hip_bfloat162(__float2bfloat16(a23.z), __float2bfloat16(a23.w)); \
    }                                                                         \
    *(int4*)&Bs[br * BSTR + bo] = b0;                                         \
  }

#define GEMM_CORE(GBIDX)                                                      \
  __shared__ unsigned short As[256 * ASTR];                                   \
  __shared__ unsigned short Bs[256 * BSTR];                                   \
  int t = threadIdx.x;                                                        \
  int lane = t & 63;                                                          \
  int wid = t >> 6;                                                           \
  int quad = lane >> 4;                                                       \
  int l16 = lane & 15;                                                        \
  int rowBase = (GBIDX) * 256;                                                \
  int mbase = (wid >> 2) * 64;                                                \
  int nbase = (wid & 3) * 64;                                                 \
  floatx4 acc[4][4];                                                          \
  _Pragma("unroll")                                                           \
  for (int i = 0; i < 4; ++i)                                                 \
    _Pragma("unroll")                                                         \
    for (int j = 0; j < 4; ++j) acc[i][j] = (floatx4){0.f, 0.f, 0.f, 0.f};    \
  int ar = t >> 2;                                                            \
  int ac = (t & 3) * 8;                                                       \
  long gm = rowBase + ar;                                                     \
  bool rowOK = (gm < M);                                                      \
  const float* aRow = (const float*)Ag + gm * (long)K;                        \
  const unsigned short* aRowB = (const unsigned short*)Ag + gm * (long)K;     \
  int br = t >> 2;                                                            \
  int bo = (t & 3) * 8;                                                       \
  const unsigned short* wRow = Wt + (size_t)br * Kpad + bo;                   \
  float4 a01, a23;                                                            \
  int4 aB;                                                                    \
  int4 b0;                                                                    \
  int KT = Kpad / 32;                                                         \
  LOAD_A(0);                                                                  \
  LOAD_B(0);                                                                  \
  for (int kt = 0; kt < KT; ++kt) {                                           \
    STORE_TILE();                                                             \
    __syncthreads();                                                          \
    if (kt + 1 < KT) {                                                        \
      int k0n = (kt + 1) * 32;                                                \
      LOAD_A(k0n);                                                            \
      LOAD_B(k0n);                                                            \
    }                                                                         \
    short8 af[4], bfr[4];                                                     \
    _Pragma("unroll")                                                         \
    for (int i = 0; i < 4; ++i)                                               \
      af[i] = *(const short8*)&As[(mbase + i * 16 + l16) * ASTR + quad * 8];  \
    _Pragma("unroll")                                                         \
    for (int j = 0; j < 4; ++j)                                               \
      bfr[j] = *(const short8*)&Bs[(nbase + j * 16 + l16) * BSTR + quad * 8]; \
    _Pragma("unroll")                                                         \
    for (int i = 0; i < 4; ++i)                                               \
      _Pragma("unroll")                                                       \
      for (int j = 0; j < 4; ++j)                                             \
        acc[i][j] = __builtin_amdgcn_mfma_f32_16x16x32_bf16(af[i], bfr[j], acc[i][j], 0, 0, 0); \
    __syncthreads();                                                          \
  }                                                                           \
  _Pragma("unroll")                                                           \
  for (int j = 0; j < 4; ++j) {                                               \
    int gn = nbase + j * 16 + l16;                                            \
    if (gn >= Ncol) continue;                                                 \
    float bv = bias ? bias[gn] : 0.f;                                         \
    _Pragma("unroll")                                                         \
    for (int i = 0; i < 4; ++i) {                                             \
      int gm0 = rowBase + mbase + i * 16 + quad * 4;                          \
      _Pragma("unroll")                                                       \
      for (int r = 0; r < 4; ++r) {                                           \
        int gmm = gm0 + r;                                                    \
        if (gmm < M) Cg[(long)gmm * Ncol + gn] = f2bf(acc[i][j][r] + bv);     \
      }                                                                       \
    }                                                                         \
  }

// plain GEMM (gemm2/gemm3)
__global__ __launch_bounds__(1024) void gemm_bf16_kernel(
    const void* __restrict__ Ag, const unsigned short* __restrict__ Wt,
    unsigned short* __restrict__ Cg, const float* __restrict__ bias,
    int M, int K, int Kpad, int Ncol, int aBf16) {
  GEMM_CORE(blockIdx.x)
}

// gemm1 + CSR count fused: tail blocks (>= gemmBlocks) do the edge count.
// count co-resides with gemm blocks (2048 thr/CU) and fills gemm's stalls.
__global__ __launch_bounds__(1024) void gemm_count_kernel(
    const void* __restrict__ Ag, const unsigned short* __restrict__ Wt,
    unsigned short* __restrict__ Cg, const float* __restrict__ bias,
    int M, int K, int Kpad, int Ncol, int aBf16, int gemmBlocks,
    const int* __restrict__ ei, const int* __restrict__ et,
    int* __restrict__ counts, int* __restrict__ rank) {
  if ((int)blockIdx.x >= gemmBlocks) {
    long e = (long)(blockIdx.x - gemmBlocks) * 1024 + threadIdx.x;
    if (e < Ee) {
      int col = ei[Ee + e];
      int r = et[e];
      rank[e] = atomicAdd(&counts[r * Nn + col], 1);
    }
    return;
  }
  GEMM_CORE(blockIdx.x)
}

// gemmH + node head fused: tail blocks run the node classifier on xA.
__global__ __launch_bounds__(1024) void gemm_nh_kernel(
    const void* __restrict__ Ag, const unsigned short* __restrict__ Wt,
    unsigned short* __restrict__ Cg, const float* __restrict__ bias,
    int M, int K, int Kpad, int Ncol, int aBf16, int gemmBlocks,
    const float* __restrict__ x3, const float* __restrict__ nw1,
    const float* __restrict__ nb1, const float* __restrict__ nw2,
    const float* __restrict__ nb2, float* __restrict__ outN) {
  if ((int)blockIdx.x >= gemmBlocks) {
    __shared__ float w1s[64 * 32];
    __shared__ float w2s[64];
    for (int i = threadIdx.x; i < 2048; i += 1024) w1s[i] = nw1[i];
    if (threadIdx.x < 64) w2s[threadIdx.x] = nw2[threadIdx.x];
    __syncthreads();
    int n = (blockIdx.x - gemmBlocks) * 1024 + threadIdx.x;
    if (n >= Nn) return;
    float accv[32];
#pragma unroll
    for (int c = 0; c < 32; ++c) accv[c] = nb1[c];
    for (int k = 0; k < 64; ++k) {
      float xv = x3[(long)n * 64 + k];
#pragma unroll
      for (int c = 0; c < 32; ++c) accv[c] += xv * w1s[k * 32 + c];
    }
    float l0 = nb2[0], l1 = nb2[1];
#pragma unroll
    for (int c = 0; c < 32; ++c) {
      float h = fmaxf(accv[c], 0.f);
      l0 += h * w2s[c * 2 + 0];
      l1 += h * w2s[c * 2 + 1];
    }
    float mx = fmaxf(l0, l1);
    float ls = mx + logf(expf(l0 - mx) + expf(l1 - mx));
    outN[(long)3 * Ee + (long)n * 2 + 0] = l0 - ls;
    outN[(long)3 * Ee + (long)n * 2 + 1] = l1 - ls;
    return;
  }
  GEMM_CORE(blockIdx.x)
}

// ---------------------------------------------------------------------------
// Aggregation v5 (bf16 XR): flattened 3-relation loop + 2-deep gather unroll.
// Mode 0: bf16 out. Mode 1: fp32 out + optional bf16 copy (outh) for gemmH.
// ---------------------------------------------------------------------------
#define AGG_RESOLVE(ii, ee, vv, rr)                                   \
  {                                                                   \
    if ((ii) < c0)       { ee = b0 + (ii);         vv = inv0; rr = 0; }   \
    else if ((ii) < c01) { ee = b1 + ((ii) - c0);  vv = inv1; rr = 64; }  \
    else                 { ee = b2 + ((ii) - c01); vv = inv2; rr = 128; } \
  }
#define AGG_FMA8(v, inv)                                              \
  {                                                                   \
    unsigned u0 = (unsigned)v.x, u1 = (unsigned)v.y;                  \
    unsigned u2 = (unsigned)v.z, u3 = (unsigned)v.w;                  \
    a0 = fmaf(__int_as_float(u0 << 16), inv, a0);                     \
    a1 = fmaf(__int_as_float(u0 & 0xffff0000u), inv, a1);             \
    a2 = fmaf(__int_as_float(u1 << 16), inv, a2);                     \
    a3 = fmaf(__int_as_float(u1 & 0xffff0000u), inv, a3);             \
    a4 = fmaf(__int_as_float(u2 << 16), inv, a4);                     \
    a5 = fmaf(__int_as_float(u2 & 0xffff0000u), inv, a5);             \
    a6 = fmaf(__int_as_float(u3 << 16), inv, a6);                     \
    a7 = fmaf(__int_as_float(u3 & 0xffff0000u), inv, a7);             \
  }

__global__ __launch_bounds__(256) void agg_kernel(const unsigned short* __restrict__ XR,
                                                  const int* __restrict__ offs,
                                                  const int* __restrict__ srcs,
                                                  const float* __restrict__ bias,
                                                  const float* __restrict__ lng,
                                                  const float* __restrict__ lnb,
                                                  float* __restrict__ out,
                                                  unsigned short* __restrict__ outh,
                                                  int mode) {
  int lane = threadIdx.x & 63;
  int wid = threadIdx.x >> 6;
  int slot = lane >> 3;     // 0..7 : edge slot
  int l8 = lane & 7;        // h-chunk: h = l8*8 .. l8*8+7
  int dst = blockIdx.x * 4 + wid;
  if (dst >= Nn) return;

  int b0 = offs[dst],          e0 = offs[dst + 1];
  int b1 = offs[Nn + dst],     e1 = offs[Nn + dst + 1];
  int b2 = offs[2 * Nn + dst], e2 = offs[2 * Nn + dst + 1];
  int c0 = e0 - b0, c1 = e1 - b1, c2 = e2 - b2;
  int c01 = c0 + c1;
  int tot = c01 + c2;
  float inv0 = (c0 > 0) ? 1.f / (float)c0 : 0.f;
  float inv1 = (c1 > 0) ? 1.f / (float)c1 : 0.f;
  float inv2 = (c2 > 0) ? 1.f / (float)c2 : 0.f;

  float a0 = 0.f, a1 = 0.f, a2 = 0.f, a3 = 0.f;
  float a4 = 0.f, a5 = 0.f, a6 = 0.f, a7 = 0.f;
  for (int i = slot; i < tot; i += 16) {
    int ea; float iva; int ra;
    AGG_RESOLVE(i, ea, iva, ra);
    int ib = i + 8;
    int eb; float ivb; int rb;
    if (ib < tot) { AGG_RESOLVE(ib, eb, ivb, rb); }
    else          { eb = ea; ivb = 0.f; rb = ra; }
    int sa = srcs[ea];
    int sb = srcs[eb];
    int4 va = *(const int4*)&XR[(long)sa * 256 + ra + l8 * 8];
    int4 vb = *(const int4*)&XR[(long)sb * 256 + rb + l8 * 8];
    AGG_FMA8(va, iva);
    AGG_FMA8(vb, ivb);
  }
#pragma unroll
  for (int m = 8; m < 64; m <<= 1) {
    a0 += __shfl_xor(a0, m, 64); a1 += __shfl_xor(a1, m, 64);
    a2 += __shfl_xor(a2, m, 64); a3 += __shfl_xor(a3, m, 64);
    a4 += __shfl_xor(a4, m, 64); a5 += __shfl_xor(a5, m, 64);
    a6 += __shfl_xor(a6, m, 64); a7 += __shfl_xor(a7, m, 64);
  }

  int4 rt = *(const int4*)&XR[(long)dst * 256 + 192 + l8 * 8];
  unsigned r0 = (unsigned)rt.x, r1 = (unsigned)rt.y;
  unsigned r2 = (unsigned)rt.z, r3 = (unsigned)rt.w;
  float4 bv0 = *(const float4*)&bias[l8 * 8];
  float4 bv1 = *(const float4*)&bias[l8 * 8 + 4];
  float t0 = a0 + __int_as_float(r0 << 16) + bv0.x;
  float t1 = a1 + __int_as_float(r0 & 0xffff0000u) + bv0.y;
  float t2 = a2 + __int_as_float(r1 << 16) + bv0.z;
  float t3 = a3 + __int_as_float(r1 & 0xffff0000u) + bv0.w;
  float t4 = a4 + __int_as_float(r2 << 16) + bv1.x;
  float t5 = a5 + __int_as_float(r2 & 0xffff0000u) + bv1.y;
  float t6 = a6 + __int_as_float(r3 << 16) + bv1.z;
  float t7 = a7 + __int_as_float(r3 & 0xffff0000u) + bv1.w;

  if (mode == 0) {
    if (slot == 0) {
      unsigned short* outB = (unsigned short*)out;
      int4 o;
      o.x = (int)((unsigned)f2bf(fmaxf(t0, 0.f)) | ((unsigned)f2bf(fmaxf(t1, 0.f)) << 16));
      o.y = (int)((unsigned)f2bf(fmaxf(t2, 0.f)) | ((unsigned)f2bf(fmaxf(t3, 0.f)) << 16));
      o.z = (int)((unsigned)f2bf(fmaxf(t4, 0.f)) | ((unsigned)f2bf(fmaxf(t5, 0.f)) << 16));
      o.w = (int)((unsigned)f2bf(fmaxf(t6, 0.f)) | ((unsigned)f2bf(fmaxf(t7, 0.f)) << 16));
      *(int4*)&outB[(long)dst * 64 + l8 * 8] = o;
    }
  } else {
    float s = t0 + t1 + t2 + t3 + t4 + t5 + t6 + t7;
    s += __shfl_xor(s, 1, 64); s += __shfl_xor(s, 2, 64); s += __shfl_xor(s, 4, 64);
    float mu = s * (1.f / 64.f);
    float d0 = t0 - mu, d1 = t1 - mu, d2 = t2 - mu, d3 = t3 - mu;
    float d4 = t4 - mu, d5 = t5 - mu, d6 = t6 - mu, d7 = t7 - mu;
    float vv = d0 * d0 + d1 * d1 + d2 * d2 + d3 * d3 +
               d4 * d4 + d5 * d5 + d6 * d6 + d7 * d7;
    vv += __shfl_xor(vv, 1, 64); vv += __shfl_xor(vv, 2, 64); vv += __shfl_xor(vv, 4, 64);
    float rstd = rsqrtf(vv * (1.f / 64.f) + 1e-5f);
    if (slot == 0) {
      float4 g0 = *(const float4*)&lng[l8 * 8];
      float4 g1 = *(const float4*)&lng[l8 * 8 + 4];
      float4 c0v = *(const float4*)&lnb[l8 * 8];
      float4 c1v = *(const float4*)&lnb[l8 * 8 + 4];
      float4 o0, o1;
      o0.x = d0 * rstd * g0.x + c0v.x;
      o0.y = d1 * rstd * g0.y + c0v.y;
      o0.z = d2 * rstd * g0.z + c0v.z;
      o0.w = d3 * rstd * g0.w + c0v.w;
      o1.x = d4 * rstd * g1.x + c1v.x;
      o1.y = d5 * rstd * g1.y + c1v.y;
      o1.z = d6 * rstd * g1.z + c1v.z;
      o1.w = d7 * rstd * g1.w + c1v.w;
      *(float4*)&out[(long)dst * 64 + l8 * 8] = o0;
      *(float4*)&out[(long)dst * 64 + l8 * 8 + 4] = o1;
      if (outh) {
        int4 oh;
        oh.x = (int)((unsigned)f2bf(o0.x) | ((unsigned)f2bf(o0.y) << 16));
        oh.y = (int)((unsigned)f2bf(o0.z) | ((unsigned)f2bf(o0.w) << 16));
        oh.z = (int)((unsigned)f2bf(o1.x) | ((unsigned)f2bf(o1.y) << 16));
        oh.w = (int)((unsigned)f2bf(o1.z) | ((unsigned)f2bf(o1.w) << 16));
        *(int4*)&outh[(long)dst * 64 + l8 * 8] = oh;
      }
    }
  }
}

// ---------------------------------------------------------------------------
// Edge head v3: 8 lanes per edge, each lane exactly ONE int4 per endpoint
// (8 h values, 24 FMAs); 3-level shfl; sublane 0 does log-softmax + write.
// ---------------------------------------------------------------------------
__global__ __launch_bounds__(256) void edge_head_kernel(const unsigned short* __restrict__ AB,
                                                        const int* __restrict__ ei,
                                                        const float* __restrict__ ew2,
                                                        const float* __restrict__ eb2,
                                                        float* __restrict__ out) {
  int t = threadIdx.x;
  long e = (long)blockIdx.x * 32 + (t >> 3);
  if (e >= Ee) return;
  int sub = t & 7;
  int row = ei[e];
  int col = ei[Ee + e];
  int4 av = *(const int4*)&AB[(long)row * 128 + sub * 8];
  int4 bv = *(const int4*)&AB[(long)col * 128 + 64 + sub * 8];
  float acc0 = 0.f, acc1 = 0.f, acc2 = 0.f;
  const int* ad = (const int*)&av;
  const int* bd = (const int*)&bv;
#pragma unroll
  for (int d = 0; d < 4; ++d) {
    int A = ad[d], B = bd[d];
    float a0 = __int_as_float(A << 16);
    float a1 = __int_as_float(A & 0xffff0000);
    float b0 = __int_as_float(B << 16);
    float b1 = __int_as_float(B & 0xffff0000);
    float e0 = fmaxf(a0 + b0, 0.f);
    float e1 = fmaxf(a1 + b1, 0.f);
    int h = sub * 8 + d * 2;
    acc0 = fmaf(e0, ew2[h * 3 + 0], acc0);
    acc1 = fmaf(e0, ew2[h * 3 + 1], acc1);
    acc2 = fmaf(e0, ew2[h * 3 + 2], acc2);
    acc0 = fmaf(e1, ew2[h * 3 + 3], acc0);
    acc1 = fmaf(e1, ew2[h * 3 + 4], acc1);
    acc2 = fmaf(e1, ew2[h * 3 + 5], acc2);
  }
  acc0 += __shfl_xor(acc0, 1, 64); acc0 += __shfl_xor(acc0, 2, 64); acc0 += __shfl_xor(acc0, 4, 64);
  acc1 += __shfl_xor(acc1, 1, 64); acc1 += __shfl_xor(acc1, 2, 64); acc1 += __shfl_xor(acc1, 4, 64);
  acc2 += __shfl_xor(acc2, 1, 64); acc2 += __shfl_xor(acc2, 2, 64); acc2 += __shfl_xor(acc2, 4, 64);
  if (sub == 0) {
    float l0 = acc0 + eb2[0], l1 = acc1 + eb2[1], l2 = acc2 + eb2[2];
    float mx = fmaxf(l0, fmaxf(l1, l2));
    float ls = mx + logf(expf(l0 - mx) + expf(l1 - mx) + expf(l2 - mx));
    out[e * 3 + 0] = l0 - ls;
    out[e * 3 + 1] = l1 - ls;
    out[e * 3 + 2] = l2 - ls;
  }
}

// ---------------------------------------------------------------------------
extern "C" void kernel_launch(void* const* d_in, const int* in_sizes, int n_in,
                              void* d_out, int out_size, void* d_ws, size_t ws_size,
                              hipStream_t stream) {
  const float* x = (const float*)d_in[0];
  const int* ei = (const int*)d_in[1];
  const int* et = (const int*)d_in[2];
  const float* W1 = (const float*)d_in[3];
  const float* root1 = (const float*)d_in[4];
  const float* b1 = (const float*)d_in[5];
  const float* W2 = (const float*)d_in[6];
  const float* root2 = (const float*)d_in[7];
  const float* b2 = (const float*)d_in[8];
  const float* W3 = (const float*)d_in[9];
  const float* root3 = (const float*)d_in[10];
  const float* b3 = (const float*)d_in[11];
  const float* lng = (const float*)d_in[12];
  const float* lnb = (const float*)d_in[13];
  const float* ew1 = (const float*)d_in[14];
  const float* eb1 = (const float*)d_in[15];
  const float* ew2 = (const float*)d_in[16];
  const float* eb2 = (const float*)d_in[17];
  const float* nw1 = (const float*)d_in[18];
  const float* nb1 = (const float*)d_in[19];
  const float* nw2 = (const float*)d_in[20];
  const float* nb2 = (const float*)d_in[21];
  float* out = (float*)d_out;

  char* p = (char*)d_ws;
  size_t off = 0;
  auto alloc = [&](size_t bytes) {
    void* r = p + off;
    off += (bytes + 255) & ~(size_t)255;
    return r;
  };
  // Workspace kept within the proven footprint: rank/counts/xh ALIAS xA/xB
  // (liveness windows verified disjoint; see launch-order comments).
  unsigned short* XR = (unsigned short*)alloc((size_t)Nn * 256 * 2);  // bf16; also AB
  float* xA = (float*)alloc((size_t)Nn * 64 * 4);
  float* xB = (float*)alloc((size_t)Nn * 64 * 4);
  int* srcs = (int*)alloc((size_t)Ee * 4);
  int* offs = (int*)alloc((size_t)(RN + 1) * 4);
  int* bsums = (int*)alloc(1024);
  unsigned short* Wt1 = (unsigned short*)alloc((size_t)256 * KPAD1 * 2);
  unsigned short* Wt2 = (unsigned short*)alloc((size_t)256 * 64 * 2);
  unsigned short* Wt3 = (unsigned short*)alloc((size_t)256 * 64 * 2);
  unsigned short* Wth = (unsigned short*)alloc((size_t)256 * 64 * 2);
  float* biasH = (float*)alloc(128 * 4);
  int* rank = (int*)xA;                 // dead before agg1 writes xA
  int* counts = (int*)xB;               // dead (post-scan) before agg2 writes xB
  unsigned short* xh = (unsigned short*)xB;  // LN bf16 copy; xB dead after gemm3

  int nb = (RN + 1023) / 1024;  // 147
  int gemmBlocks = (Nn + 255) / 256;  // 196
  int aggBlocks = (Nn + 3) / 4;
  int countBlocks = (Ee + 1023) / 1024;  // 1563
  int nhBlocks = (Nn + 1023) / 1024;     // 49

  // --- weight prep (no deps) ---
  prep_wt_kernel<<<(256 * KPAD1 + 255) / 256, 256, 0, stream>>>(W1, root1, Wt1, FIN, KPAD1);
  prep_wt_kernel<<<(256 * 64 + 255) / 256, 256, 0, stream>>>(W2, root2, Wt2, 64, 64);
  prep_wt_kernel<<<(256 * 64 + 255) / 256, 256, 0, stream>>>(W3, root3, Wt3, 64, 64);
  prep_wth_kernel<<<(256 * 64 + 255) / 256, 256, 0, stream>>>(ew1, eb1, Wth, biasH);
  hipMemsetAsync(counts, 0, (size_t)RN * 4, stream);

  // --- layer 1 GEMM fused with CSR count (count fills gemm's idle CUs/stalls) ---
  gemm_count_kernel<<<gemmBlocks + countBlocks, 1024, 0, stream>>>(
      x, Wt1, XR, nullptr, Nn, FIN, KPAD1, 256, 0, gemmBlocks, ei, et, counts, rank);

  // --- CSR scan + fill ---
  scan1_kernel<<<nb, 256, 0, stream>>>(counts, offs, bsums, RN);
  scan_top_kernel<<<1, 256, 0, stream>>>(bsums, nb);
  scan_add_kernel<<<(RN + 256) / 256 + 1, 256, 0, stream>>>(offs, bsums, RN);
  fill_kernel<<<(Ee + 255) / 256, 256, 0, stream>>>(ei, et, offs, rank, srcs);

  // --- layer 1 agg (kills rank) ---
  agg_kernel<<<aggBlocks, 256, 0, stream>>>(XR, offs, srcs, b1, nullptr, nullptr, xA, nullptr, 0);
  // --- layer 2 ---
  gemm_bf16_kernel<<<gemmBlocks, 1024, 0, stream>>>(xA, Wt2, XR, nullptr, Nn, 64, 64, 256, 1);
  agg_kernel<<<aggBlocks, 256, 0, stream>>>(XR, offs, srcs, b2, nullptr, nullptr, xB, nullptr, 0);
  // --- layer 3 + layernorm (fp32 -> xA, bf16 copy -> xh) ---
  gemm_bf16_kernel<<<gemmBlocks, 1024, 0, stream>>>(xB, Wt3, XR, nullptr, Nn, 64, 64, 256, 1);
  agg_kernel<<<aggBlocks, 256, 0, stream>>>(XR, offs, srcs, b3, lng, lnb, xA, xh, 1);
  // --- heads: gemmH fused with node head ---
  gemm_nh_kernel<<<gemmBlocks + nhBlocks, 1024, 0, stream>>>(
      xh, Wth, XR, biasH, Nn, 64, 64, 128, 1, gemmBlocks,
      xA, nw1, nb1, nw2, nb2, out);
  edge_head_kernel<<<(Ee + 31) / 32, 256, 0, stream>>>(XR, ei, ew2, eb2, out);
}